// Round 1
// baseline (1715.479 us; speedup 1.0000x reference)
//
#include <hip/hip_runtime.h>
#include <hip/hip_bf16.h>

constexpr int kB = 32;
constexpr int kN = 256;
constexpr int kR = 2048;
constexpr int kD = 1024;

typedef short bf16x8 __attribute__((ext_vector_type(8)));
typedef float f32x4 __attribute__((ext_vector_type(4)));
typedef unsigned short u16x8 __attribute__((ext_vector_type(8)));

__device__ __forceinline__ unsigned short f2bf(float f) {
  union { __hip_bfloat16 h; unsigned short u; } cv;
  cv.h = __float2bfloat16(f);
  return cv.u;
}

__device__ __forceinline__ void cvt_store8(unsigned short* dst, float4 x, float4 y) {
  u16x8 v;
  v[0] = f2bf(x.x); v[1] = f2bf(x.y); v[2] = f2bf(x.z); v[3] = f2bf(x.w);
  v[4] = f2bf(y.x); v[5] = f2bf(y.y); v[6] = f2bf(y.z); v[7] = f2bf(y.w);
  *reinterpret_cast<u16x8*>(dst) = v;
}

// C[m,d] = relu( sum_k A[m,k] * W[d,k] + bias[d] ) + resid[m,d]  (*mask[m] if rela)
// A rows are a concat of segments, each 1024 wide (16 k-steps of 64):
//   attr: [obj_row, attr_row]              (K=2048)
//   rela: [obj[subj], rela_row, obj[obji]] (K=3072)
template <bool IS_RELA, int K_TOT, int ROWS_PER_B>
__global__ __launch_bounds__(256, 2) void gnn_gemm(
    const float* __restrict__ obj, const float* __restrict__ resid,
    const int* __restrict__ edges, const float* __restrict__ masks,
    const float* __restrict__ W, const float* __restrict__ bias,
    float* __restrict__ out) {
  constexpr int T = K_TOT / 64;
  __shared__ unsigned short sA[2][128 * 64];
  __shared__ unsigned short sB[2][128 * 64];

  const int tid = threadIdx.x;
  const int row0 = blockIdx.y * 128;
  const int col0 = blockIdx.x * 128;

  // ---------------- staging identity: 2 threads per row, 32 floats each ----
  const int srow = tid >> 1;   // 0..127
  const int sseg = tid & 1;    // which 32-float half of the 64-wide k-step
  const int m_s = row0 + srow;
  const int b_s = m_s / ROWS_PER_B;
  const int r_s = m_s & (ROWS_PER_B - 1);

  const float* aseg0;
  const float* aseg1;
  const float* aseg2 = nullptr;
  if constexpr (IS_RELA) {
    const int2 e =
        *reinterpret_cast<const int2*>(&edges[((size_t)b_s * kR + r_s) * 2]);
    aseg0 = obj + ((size_t)b_s * kN + e.x) * kD;
    aseg1 = resid + ((size_t)b_s * kR + r_s) * kD;
    aseg2 = obj + ((size_t)b_s * kN + e.y) * kD;
  } else {
    aseg0 = obj + ((size_t)b_s * kN + r_s) * kD;
    aseg1 = resid + ((size_t)b_s * kN + r_s) * kD;
  }
  const float* wrow = W + (size_t)(col0 + srow) * K_TOT + sseg * 32;

  const int wbase = srow * 64;
  const int swz_w = (srow & 7) << 3;  // XOR swizzle, 8-element (16B) granules

  // ---------------- compute identity: 2x2 waves, 64x64 each ----------------
  const int wid = tid >> 6;
  const int lane = tid & 63;
  const int wr = wid >> 1;
  const int wc = wid & 1;
  const int lrow = lane & 15;
  const int lgrp = lane >> 4;
  const int swz_r = (lrow & 7) << 3;

  f32x4 acc[4][4] = {};
  float4 ra[8], rb[8];

  // prologue: load tile 0 into regs
  {
    const float* ap = aseg0 + sseg * 32;
#pragma unroll
    for (int j = 0; j < 8; ++j)
      ra[j] = *reinterpret_cast<const float4*>(ap + j * 4);
#pragma unroll
    for (int j = 0; j < 8; ++j)
      rb[j] = *reinterpret_cast<const float4*>(wrow + j * 4);
  }

#pragma unroll 2
  for (int t = 0; t < T; ++t) {
    unsigned short* da = sA[t & 1];
    unsigned short* db = sB[t & 1];

    // convert f32->bf16 + swizzled LDS write (waits on last iter's loads)
#pragma unroll
    for (int j = 0; j < 4; ++j)
      cvt_store8(&da[wbase + ((sseg * 32 + j * 8) ^ swz_w)], ra[2 * j],
                 ra[2 * j + 1]);
#pragma unroll
    for (int j = 0; j < 4; ++j)
      cvt_store8(&db[wbase + ((sseg * 32 + j * 8) ^ swz_w)], rb[2 * j],
                 rb[2 * j + 1]);

    __syncthreads();

    // prefetch tile t+1 (issued after the barrier so its vmcnt(0) drain
    // doesn't serialize these; they complete under the MFMA phase below)
    if (t + 1 < T) {
      const int tn = t + 1;
      const float* s01 = (tn < 16) ? aseg0 : aseg1;
      const float* ssrc = (IS_RELA && tn >= 32) ? aseg2 : s01;
      const float* ap = ssrc + (tn & 15) * 64 + sseg * 32;
      const float* wp = wrow + tn * 64;
#pragma unroll
      for (int j = 0; j < 8; ++j)
        ra[j] = *reinterpret_cast<const float4*>(ap + j * 4);
#pragma unroll
      for (int j = 0; j < 8; ++j)
        rb[j] = *reinterpret_cast<const float4*>(wp + j * 4);
    }

    // compute from buf[t&1]
#pragma unroll
    for (int kk = 0; kk < 2; ++kk) {
      bf16x8 af[4], bfr[4];
#pragma unroll
      for (int mi = 0; mi < 4; ++mi) {
        const int row = wr * 64 + mi * 16 + lrow;
        af[mi] = *reinterpret_cast<const bf16x8*>(
            &da[row * 64 + ((kk * 32 + lgrp * 8) ^ swz_r)]);
      }
#pragma unroll
      for (int ni = 0; ni < 4; ++ni) {
        const int row = wc * 64 + ni * 16 + lrow;
        bfr[ni] = *reinterpret_cast<const bf16x8*>(
            &db[row * 64 + ((kk * 32 + lgrp * 8) ^ swz_r)]);
      }
#pragma unroll
      for (int mi = 0; mi < 4; ++mi)
#pragma unroll
        for (int ni = 0; ni < 4; ++ni)
          acc[mi][ni] = __builtin_amdgcn_mfma_f32_16x16x32_bf16(
              af[mi], bfr[ni], acc[mi][ni], 0, 0, 0);
    }
  }

  // ---------------- epilogue: bias + relu + residual (+mask) ---------------
  float biasv[4];
#pragma unroll
  for (int ni = 0; ni < 4; ++ni)
    biasv[ni] = bias[col0 + wc * 64 + ni * 16 + lrow];

#pragma unroll
  for (int mi = 0; mi < 4; ++mi) {
#pragma unroll
    for (int j = 0; j < 4; ++j) {
      const int m = row0 + wr * 64 + mi * 16 + lgrp * 4 + j;
      const size_t ro = (size_t)m * kD;
      float mk = 1.0f;
      if constexpr (IS_RELA) mk = masks[m];
#pragma unroll
      for (int ni = 0; ni < 4; ++ni) {
        const int col = col0 + wc * 64 + ni * 16 + lrow;
        float v = acc[mi][ni][j] + biasv[ni];
        v = fmaxf(v, 0.0f) + resid[ro + col];
        if constexpr (IS_RELA) v *= mk;
        out[ro + col] = v;
      }
    }
  }
}

extern "C" void kernel_launch(void* const* d_in, const int* in_sizes, int n_in,
                              void* d_out, int out_size, void* d_ws,
                              size_t ws_size, hipStream_t stream) {
  (void)in_sizes; (void)n_in; (void)out_size; (void)d_ws; (void)ws_size;
  const float* obj = (const float*)d_in[0];
  const float* attr = (const float*)d_in[1];
  const float* rela = (const float*)d_in[2];
  const int* edges = (const int*)d_in[3];
  const float* masks = (const float*)d_in[4];
  const float* W_attr = (const float*)d_in[5];
  const float* b_attr = (const float*)d_in[6];
  const float* W_rela = (const float*)d_in[7];
  const float* b_rela = (const float*)d_in[8];

  float* out0 = (float*)d_out;
  float* out1 = out0 + (size_t)kB * kN * kD;
  float* out2 = out1 + (size_t)kB * kN * kD;

  // out0: obj_vecs passthrough
  hipMemcpyAsync(out0, obj, (size_t)kB * kN * kD * sizeof(float),
                 hipMemcpyDeviceToDevice, stream);

  // out1: new_attr_vecs  (M = B*N = 8192, K = 2048)
  gnn_gemm<false, 2048, kN>
      <<<dim3(kD / 128, (kB * kN) / 128), 256, 0, stream>>>(
          obj, attr, nullptr, nullptr, W_attr, b_attr, out1);

  // out2: new_rela_vecs  (M = B*R = 65536, K = 3072)
  gnn_gemm<true, 3072, kR>
      <<<dim3(kD / 128, (kB * kR) / 128), 256, 0, stream>>>(
          obj, rela, edges, masks, W_rela, b_rela, out2);
}

// Round 2
// 975.003 us; speedup vs baseline: 1.7595x; 1.7595x over previous
//
#include <hip/hip_runtime.h>
#include <hip/hip_bf16.h>

constexpr int kB = 32;
constexpr int kN = 256;
constexpr int kR = 2048;
constexpr int kD = 1024;

typedef short bf16x8 __attribute__((ext_vector_type(8)));
typedef float f32x4 __attribute__((ext_vector_type(4)));
typedef unsigned short u16x8 __attribute__((ext_vector_type(8)));

__device__ __forceinline__ unsigned short f2bf(float f) {
  union { __hip_bfloat16 h; unsigned short u; } cv;
  cv.h = __float2bfloat16(f);
  return cv.u;
}

__device__ __forceinline__ void gload_lds16(const void* g, void* l) {
  __builtin_amdgcn_global_load_lds(
      (const __attribute__((address_space(1))) unsigned int*)g,
      (__attribute__((address_space(3))) unsigned int*)l, 16, 0, 0);
}

// ---------------------------------------------------------------------------
// f32 -> bf16 pre-pass (vectorized 8/thread, grid-stride)
// ---------------------------------------------------------------------------
__global__ void cvt_f32_bf16(const float* __restrict__ in,
                             unsigned short* __restrict__ out, int n8) {
  const int stride = gridDim.x * blockDim.x;
  for (int i = blockIdx.x * blockDim.x + threadIdx.x; i < n8; i += stride) {
    const float4 a = reinterpret_cast<const float4*>(in)[2 * i];
    const float4 b = reinterpret_cast<const float4*>(in)[2 * i + 1];
    u16x8 v;
    v[0] = f2bf(a.x); v[1] = f2bf(a.y); v[2] = f2bf(a.z); v[3] = f2bf(a.w);
    v[4] = f2bf(b.x); v[5] = f2bf(b.y); v[6] = f2bf(b.z); v[7] = f2bf(b.w);
    reinterpret_cast<u16x8*>(out)[i] = v;
  }
}

// ---------------------------------------------------------------------------
// bf16 GEMM, 128x128 tile, BK=64, global_load_lds staging, m97 2-phase loop.
// C[m,d] = relu(sum_k A[m,k]*W[d,k] + bias[d]) + resid[m,d]  (*mask[m] if rela)
// A row = concat of 1024-wide segments:
//   attr: [objb row m, attrb row m]               (K=2048)
//   rela: [objb[subj], relab row m, objb[obji]]   (K=3072)
// LDS: linear dest (global_load_lds), XOR-swizzled 16B granules via
// pre-swizzled global source + swizzled ds_read (rule #21).
// ---------------------------------------------------------------------------
template <bool IS_RELA, int K_TOT, int LOG_RPB>
__global__ __launch_bounds__(256, 2) void gnn_gemm_bf16(
    const unsigned short* __restrict__ objb,
    const unsigned short* __restrict__ seg1b,   // attrb or relab
    const unsigned short* __restrict__ Wb,
    const int* __restrict__ edges, const float* __restrict__ masks,
    const float* __restrict__ resid, const float* __restrict__ bias,
    float* __restrict__ out, int rbx /* row-blocks per XCD */) {
  constexpr int T = K_TOT / 64;
  __shared__ unsigned short sA[2][128 * 64];
  __shared__ unsigned short sB[2][128 * 64];

  // XCD-locality block mapping: the 8 col-blocks of one row-panel land on
  // the same XCD (bid%8) and adjacent in its local sequence.
  const int bid = blockIdx.x;
  const int x = bid & 7;
  const int j = bid >> 3;
  const int row0 = (x * rbx + (j >> 3)) * 128;
  const int col0 = (j & 7) * 128;

  const int tid = threadIdx.x;
  const int w = tid >> 6;   // wave 0..3
  const int l = tid & 63;

  // -------- per-lane staging offsets (bytes, uint32) ----------------------
  // wave w, instruction i stages rows w*32+i*8 .. +7; lane: r=l>>3, g=l&7.
  uint32_t offA0[4], offA1[4], offA2[4], offB[4];
#pragma unroll
  for (int i = 0; i < 4; ++i) {
    const int m = row0 + w * 32 + i * 8 + (l >> 3);
    if constexpr (IS_RELA) {
      const int b = m >> LOG_RPB;
      const int r = m & ((1 << LOG_RPB) - 1);
      const int2 e =
          *reinterpret_cast<const int2*>(&edges[((size_t)b * kR + r) * 2]);
      offA0[i] = (uint32_t)(((size_t)(b * kN + e.x) * kD) * 2);
      offA1[i] = (uint32_t)((size_t)m * kD * 2);
      offA2[i] = (uint32_t)(((size_t)(b * kN + e.y) * kD) * 2);
    } else {
      offA0[i] = (uint32_t)((size_t)m * kD * 2);  // obj & attr share index m
      offA1[i] = offA0[i];
      offA2[i] = 0;
    }
    const int c = col0 + w * 32 + i * 8 + (l >> 3);
    offB[i] = (uint32_t)((size_t)c * K_TOT * 2);
  }
  // source pre-swizzle: LDS slot (r,g) receives global granule g^(r&7)
  const int sw16 = (((l & 7) ^ (l >> 3)) << 4);

  // -------- compute identity: 2x2 waves, 64x64 each -----------------------
  const int wr = w >> 1;
  const int wc = w & 1;
  const int lrow = l & 15;
  const int lgrp = l >> 4;

  f32x4 acc[4][4] = {};

  auto stage = [&](int t, int cur) {
#pragma unroll
    for (int i = 0; i < 4; ++i) {
      const unsigned short* bA;
      uint32_t oA;
      if constexpr (IS_RELA) {
        if (t < 16)      { bA = objb;  oA = offA0[i]; }
        else if (t < 32) { bA = seg1b; oA = offA1[i]; }
        else             { bA = objb;  oA = offA2[i]; }
      } else {
        bA = (t < 16) ? objb : seg1b;
        oA = offA0[i];
      }
      const int ts = t & 15;
      gload_lds16((const char*)bA + oA + ts * 128 + sw16,
                  &sA[cur][(w * 32 + i * 8) * 64]);
      gload_lds16((const char*)Wb + offB[i] + t * 128 + sw16,
                  &sB[cur][(w * 32 + i * 8) * 64]);
    }
  };

  auto compute = [&](int cur) {
    const unsigned short* da = sA[cur];
    const unsigned short* db = sB[cur];
#pragma unroll
    for (int kk = 0; kk < 2; ++kk) {
      bf16x8 af[4], bfr[4];
#pragma unroll
      for (int mi = 0; mi < 4; ++mi) {
        const int row = wr * 64 + mi * 16 + lrow;
        af[mi] = *reinterpret_cast<const bf16x8*>(
            &da[row * 64 + (((kk * 4 + lgrp) ^ (lrow & 7)) << 3)]);
      }
#pragma unroll
      for (int ni = 0; ni < 4; ++ni) {
        const int row = wc * 64 + ni * 16 + lrow;
        bfr[ni] = *reinterpret_cast<const bf16x8*>(
            &db[row * 64 + (((kk * 4 + lgrp) ^ (lrow & 7)) << 3)]);
      }
#pragma unroll
      for (int mi = 0; mi < 4; ++mi)
#pragma unroll
        for (int ni = 0; ni < 4; ++ni)
          acc[mi][ni] = __builtin_amdgcn_mfma_f32_16x16x32_bf16(
              af[mi], bfr[ni], acc[mi][ni], 0, 0, 0);
    }
  };

  stage(0, 0);
  for (int t = 0; t < T; ++t) {
    __syncthreads();  // vmcnt(0) drain + barrier: tile t resident
    if (t + 1 < T) stage(t + 1, (t + 1) & 1);
    compute(t & 1);
  }

  // -------- epilogue: bias + relu + residual (+mask) ----------------------
  float biasv[4];
#pragma unroll
  for (int ni = 0; ni < 4; ++ni)
    biasv[ni] = bias[col0 + wc * 64 + ni * 16 + lrow];

#pragma unroll
  for (int mi = 0; mi < 4; ++mi) {
#pragma unroll
    for (int jj = 0; jj < 4; ++jj) {
      const int m = row0 + wr * 64 + mi * 16 + lgrp * 4 + jj;
      const size_t ro = (size_t)m * kD;
      float mk = 1.0f;
      if constexpr (IS_RELA) mk = masks[m];
#pragma unroll
      for (int ni = 0; ni < 4; ++ni) {
        const int col = col0 + wc * 64 + ni * 16 + lrow;
        float v = acc[mi][ni][jj] + biasv[ni];
        v = fmaxf(v, 0.0f) + resid[ro + col];
        if constexpr (IS_RELA) v *= mk;
        out[ro + col] = v;
      }
    }
  }
}

// ---------------------------------------------------------------------------
// Fallback (round-1 kernel, f32 reg-staged) used only if ws_size too small.
// ---------------------------------------------------------------------------
__device__ __forceinline__ void cvt_store8(unsigned short* dst, float4 x,
                                           float4 y) {
  u16x8 v;
  v[0] = f2bf(x.x); v[1] = f2bf(x.y); v[2] = f2bf(x.z); v[3] = f2bf(x.w);
  v[4] = f2bf(y.x); v[5] = f2bf(y.y); v[6] = f2bf(y.z); v[7] = f2bf(y.w);
  *reinterpret_cast<u16x8*>(dst) = v;
}

template <bool IS_RELA, int K_TOT, int ROWS_PER_B>
__global__ __launch_bounds__(256, 2) void gnn_gemm_f32(
    const float* __restrict__ obj, const float* __restrict__ resid,
    const int* __restrict__ edges, const float* __restrict__ masks,
    const float* __restrict__ W, const float* __restrict__ bias,
    float* __restrict__ out) {
  constexpr int T = K_TOT / 64;
  __shared__ unsigned short sA[2][128 * 64];
  __shared__ unsigned short sB[2][128 * 64];

  const int tid = threadIdx.x;
  const int row0 = blockIdx.y * 128;
  const int col0 = blockIdx.x * 128;

  const int srow = tid >> 1;
  const int sseg = tid & 1;
  const int m_s = row0 + srow;
  const int b_s = m_s / ROWS_PER_B;
  const int r_s = m_s & (ROWS_PER_B - 1);

  const float* aseg0;
  const float* aseg1;
  const float* aseg2 = nullptr;
  if constexpr (IS_RELA) {
    const int2 e =
        *reinterpret_cast<const int2*>(&edges[((size_t)b_s * kR + r_s) * 2]);
    aseg0 = obj + ((size_t)b_s * kN + e.x) * kD;
    aseg1 = resid + ((size_t)b_s * kR + r_s) * kD;
    aseg2 = obj + ((size_t)b_s * kN + e.y) * kD;
  } else {
    aseg0 = obj + ((size_t)b_s * kN + r_s) * kD;
    aseg1 = resid + ((size_t)b_s * kN + r_s) * kD;
  }
  const float* wrow = W + (size_t)(col0 + srow) * K_TOT + sseg * 32;

  const int wbase = srow * 64;
  const int swz_w = (srow & 7) << 3;

  const int wid = tid >> 6;
  const int lane = tid & 63;
  const int wr = wid >> 1;
  const int wc = wid & 1;
  const int lrow = lane & 15;
  const int lgrp = lane >> 4;
  const int swz_r = (lrow & 7) << 3;

  f32x4 acc[4][4] = {};
  float4 ra[8], rb[8];

  {
    const float* ap = aseg0 + sseg * 32;
#pragma unroll
    for (int j = 0; j < 8; ++j)
      ra[j] = *reinterpret_cast<const float4*>(ap + j * 4);
#pragma unroll
    for (int j = 0; j < 8; ++j)
      rb[j] = *reinterpret_cast<const float4*>(wrow + j * 4);
  }

#pragma unroll 2
  for (int t = 0; t < T; ++t) {
    unsigned short* da = sA[t & 1];
    unsigned short* db = sB[t & 1];
#pragma unroll
    for (int j = 0; j < 4; ++j)
      cvt_store8(&da[wbase + ((sseg * 32 + j * 8) ^ swz_w)], ra[2 * j],
                 ra[2 * j + 1]);
#pragma unroll
    for (int j = 0; j < 4; ++j)
      cvt_store8(&db[wbase + ((sseg * 32 + j * 8) ^ swz_w)], rb[2 * j],
                 rb[2 * j + 1]);

    __syncthreads();

    if (t + 1 < T) {
      const int tn = t + 1;
      const float* s01 = (tn < 16) ? aseg0 : aseg1;
      const float* ssrc = (IS_RELA && tn >= 32) ? aseg2 : s01;
      const float* ap = ssrc + (tn & 15) * 64 + sseg * 32;
      const float* wp = wrow + tn * 64;
#pragma unroll
      for (int j = 0; j < 8; ++j)
        ra[j] = *reinterpret_cast<const float4*>(ap + j * 4);
#pragma unroll
      for (int j = 0; j < 8; ++j)
        rb[j] = *reinterpret_cast<const float4*>(wp + j * 4);
    }

#pragma unroll
    for (int kk = 0; kk < 2; ++kk) {
      bf16x8 af[4], bfr[4];
#pragma unroll
      for (int mi = 0; mi < 4; ++mi) {
        const int row = wr * 64 + mi * 16 + lrow;
        af[mi] = *reinterpret_cast<const bf16x8*>(
            &da[row * 64 + ((kk * 32 + lgrp * 8) ^ swz_r)]);
      }
#pragma unroll
      for (int ni = 0; ni < 4; ++ni) {
        const int row = wc * 64 + ni * 16 + lrow;
        bfr[ni] = *reinterpret_cast<const bf16x8*>(
            &db[row * 64 + ((kk * 32 + lgrp * 8) ^ swz_r)]);
      }
#pragma unroll
      for (int mi = 0; mi < 4; ++mi)
#pragma unroll
        for (int ni = 0; ni < 4; ++ni)
          acc[mi][ni] = __builtin_amdgcn_mfma_f32_16x16x32_bf16(
              af[mi], bfr[ni], acc[mi][ni], 0, 0, 0);
    }
  }

  float biasv[4];
#pragma unroll
  for (int ni = 0; ni < 4; ++ni)
    biasv[ni] = bias[col0 + wc * 64 + ni * 16 + lrow];

#pragma unroll
  for (int mi = 0; mi < 4; ++mi) {
#pragma unroll
    for (int j = 0; j < 4; ++j) {
      const int m = row0 + wr * 64 + mi * 16 + lgrp * 4 + j;
      const size_t ro = (size_t)m * kD;
      float mk = 1.0f;
      if constexpr (IS_RELA) mk = masks[m];
#pragma unroll
      for (int ni = 0; ni < 4; ++ni) {
        const int col = col0 + wc * 64 + ni * 16 + lrow;
        float v = acc[mi][ni][j] + biasv[ni];
        v = fmaxf(v, 0.0f) + resid[ro + col];
        if constexpr (IS_RELA) v *= mk;
        out[ro + col] = v;
      }
    }
  }
}

extern "C" void kernel_launch(void* const* d_in, const int* in_sizes, int n_in,
                              void* d_out, int out_size, void* d_ws,
                              size_t ws_size, hipStream_t stream) {
  (void)in_sizes; (void)n_in; (void)out_size;
  const float* obj = (const float*)d_in[0];
  const float* attr = (const float*)d_in[1];
  const float* rela = (const float*)d_in[2];
  const int* edges = (const int*)d_in[3];
  const float* masks = (const float*)d_in[4];
  const float* W_attr = (const float*)d_in[5];
  const float* b_attr = (const float*)d_in[6];
  const float* W_rela = (const float*)d_in[7];
  const float* b_rela = (const float*)d_in[8];

  float* out0 = (float*)d_out;
  float* out1 = out0 + (size_t)kB * kN * kD;
  float* out2 = out1 + (size_t)kB * kN * kD;

  hipMemcpyAsync(out0, obj, (size_t)kB * kN * kD * sizeof(float),
                 hipMemcpyDeviceToDevice, stream);

  constexpr size_t nObj = (size_t)kB * kN * kD;      // 8388608
  constexpr size_t nRela = (size_t)kB * kR * kD;     // 67108864
  constexpr size_t nWa = (size_t)kD * 2 * kD;        // 2097152
  constexpr size_t nWr = (size_t)kD * 3 * kD;        // 3145728
  constexpr size_t WS_NEEDED = (nObj * 2 + nRela + nWa + nWr) * 2;

  if (ws_size >= WS_NEEDED) {
    unsigned short* objb = (unsigned short*)d_ws;
    unsigned short* attrb = objb + nObj;
    unsigned short* relab = attrb + nObj;
    unsigned short* wab = relab + nRela;
    unsigned short* wrb = wab + nWa;

    auto cvt = [&](const float* in, unsigned short* out, size_t n) {
      const int n8 = (int)(n / 8);
      const int blocks = (n8 + 255) / 256 < 8192 ? (n8 + 255) / 256 : 8192;
      cvt_f32_bf16<<<blocks, 256, 0, stream>>>(in, out, n8);
    };
    cvt(obj, objb, nObj);
    cvt(attr, attrb, nObj);
    cvt(W_attr, wab, nWa);
    cvt(rela, relab, nRela);
    cvt(W_rela, wrb, nWr);

    // attr: M=8192 -> 64 row-blocks, 8 col-blocks, 512 blocks
    gnn_gemm_bf16<false, 2048, 8><<<512, 256, 0, stream>>>(
        objb, attrb, wab, nullptr, nullptr, attr, b_attr, out1, 64 / 8);
    // rela: M=65536 -> 512 row-blocks, 8 col-blocks, 4096 blocks
    gnn_gemm_bf16<true, 3072, 11><<<4096, 256, 0, stream>>>(
        objb, relab, wrb, edges, masks, rela, b_rela, out2, 512 / 8);
  } else {
    gnn_gemm_f32<false, 2048, kN>
        <<<dim3(kD / 128, (kB * kN) / 128), 256, 0, stream>>>(
            obj, attr, nullptr, nullptr, W_attr, b_attr, out1);
    gnn_gemm_f32<true, 3072, kR>
        <<<dim3(kD / 128, (kB * kR) / 128), 256, 0, stream>>>(
            obj, rela, edges, masks, W_rela, b_rela, out2);
  }
}

// Round 3
// 903.106 us; speedup vs baseline: 1.8995x; 1.0796x over previous
//
#include <hip/hip_runtime.h>
#include <hip/hip_bf16.h>

constexpr int kB = 32;
constexpr int kN = 256;
constexpr int kR = 2048;
constexpr int kD = 1024;

typedef short bf16x8 __attribute__((ext_vector_type(8)));
typedef float f32x4 __attribute__((ext_vector_type(4)));
typedef unsigned short u16x8 __attribute__((ext_vector_type(8)));

__device__ __forceinline__ unsigned short f2bf(float f) {
  union { __hip_bfloat16 h; unsigned short u; } cv;
  cv.h = __float2bfloat16(f);
  return cv.u;
}

__device__ __forceinline__ void gload_lds16(const void* g, void* l) {
  __builtin_amdgcn_global_load_lds(
      (const __attribute__((address_space(1))) unsigned int*)g,
      (__attribute__((address_space(3))) unsigned int*)l, 16, 0, 0);
}

#define MEMFENCE asm volatile("" ::: "memory")

// ---------------------------------------------------------------------------
// f32 -> bf16 pre-pass
// ---------------------------------------------------------------------------
__global__ void cvt_f32_bf16(const float* __restrict__ in,
                             unsigned short* __restrict__ out, int n8) {
  const int stride = gridDim.x * blockDim.x;
  for (int i = blockIdx.x * blockDim.x + threadIdx.x; i < n8; i += stride) {
    const float4 a = reinterpret_cast<const float4*>(in)[2 * i];
    const float4 b = reinterpret_cast<const float4*>(in)[2 * i + 1];
    u16x8 v;
    v[0] = f2bf(a.x); v[1] = f2bf(a.y); v[2] = f2bf(a.z); v[3] = f2bf(a.w);
    v[4] = f2bf(b.x); v[5] = f2bf(b.y); v[6] = f2bf(b.z); v[7] = f2bf(b.w);
    reinterpret_cast<u16x8*>(out)[i] = v;
  }
}

// ---------------------------------------------------------------------------
// 256x256 8-phase bf16 GEMM (T2 swizzle + T3/T4 counted-drain + T5 setprio).
// C[m,d] = relu(sum_k A[m,k]*W[d,k] + bias[d]) + resid[m,d]  (*mask[m] rela)
// A row = concat of 1024-wide segments:
//   attr: [objb m, attrb m]                      (K=2048, T=32)
//   rela: [objb[subj], relab m, objb[obji]]      (K=3072, T=48)
// 8 waves = 2(M) x 4(N); per-wave C = 128x64 = 8x4 fragments of 16x16.
// LDS: 2 slots x (A 256x64 + B 256x64) bf16 = 128 KB, linear dest for
// global_load_lds, 16B-granule XOR swizzle g^=(row&7) via pre-swizzled
// global source; ds_read applies the same XOR (0 conflicts, round-2 PMC).
// Per K-tile t (slot t&1): 4 phases; phases 0-1 issue the 8 staging loads of
// tile t+1 into the opposite slot; single vmcnt(0) before phase-3's closing
// barrier makes every wave's prefetch landed before any wave reads it.
// ---------------------------------------------------------------------------
template <bool IS_RELA, int K_TOT, int LOG_RPB, int NPANEL>
__global__ __launch_bounds__(512, 2) void gnn_gemm8(
    const unsigned short* __restrict__ objb,
    const unsigned short* __restrict__ seg1b,
    const unsigned short* __restrict__ Wb,
    const int* __restrict__ edges, const float* __restrict__ masks,
    const float* __restrict__ resid, const float* __restrict__ bias,
    float* __restrict__ out) {
  constexpr int T = K_TOT / 64;
  extern __shared__ unsigned short smem[];
  unsigned short* const sA0 = smem;
  unsigned short* const sA1 = smem + 16384;
  unsigned short* const sB0 = smem + 32768;
  unsigned short* const sB1 = smem + 49152;

  // XCD mapping: XCD x owns col panel (x>>1); (x&1) splits the row panels.
  const int bid = blockIdx.x;
  const int x = bid & 7;
  const int col0 = (x >> 1) * 256;
  const int panel = (x & 1) * (NPANEL / 2) + (bid >> 3);
  const int row0 = panel * 256;

  const int tid = threadIdx.x;
  const int w = tid >> 6;   // wave 0..7
  const int l = tid & 63;

  // -------- staging offsets: load j covers rows j*64 + w*8 + (l>>3) --------
  uint32_t offA0[4], offA1[4], offA2[4], offB[4];
#pragma unroll
  for (int j = 0; j < 4; ++j) {
    const int m = row0 + j * 64 + w * 8 + (l >> 3);
    if constexpr (IS_RELA) {
      const int b = m >> LOG_RPB;
      const int r = m & ((1 << LOG_RPB) - 1);
      const int2 e =
          *reinterpret_cast<const int2*>(&edges[((size_t)b * kR + r) * 2]);
      offA0[j] = (uint32_t)(((size_t)(b * kN + e.x) * kD) * 2);
      offA1[j] = (uint32_t)((size_t)m * kD * 2);
      offA2[j] = (uint32_t)(((size_t)(b * kN + e.y) * kD) * 2);
    } else {
      offA0[j] = (uint32_t)((size_t)m * kD * 2);
      offA1[j] = offA0[j];
      offA2[j] = 0;
    }
    const int c = col0 + j * 64 + w * 8 + (l >> 3);
    offB[j] = (uint32_t)((size_t)c * K_TOT * 2);
  }
  const int sw16 = (((l & 7) ^ (l >> 3)) << 4);  // source pre-swizzle (bytes)

  // -------- compute identity --------------------------------------------
  const int wr = w >> 2;        // 0..1  (M half)
  const int wc = w & 3;         // 0..3  (N quarter)
  const int lrow = l & 15;
  const int lgrp = l >> 4;

  f32x4 acc[8][4] = {};

  auto stageA = [&](unsigned short* dst, int tn, int j) {
    const unsigned short* base;
    uint32_t off;
    if constexpr (IS_RELA) {
      if (tn < 16)      { base = objb;  off = offA0[j]; }
      else if (tn < 32) { base = seg1b; off = offA1[j]; }
      else              { base = objb;  off = offA2[j]; }
    } else {
      base = (tn < 16) ? objb : seg1b;
      off = offA0[j];
    }
    gload_lds16((const char*)base + off + (tn & 15) * 128 + sw16,
                dst + (j * 64 + w * 8) * 64);
  };
  auto stageB = [&](unsigned short* dst, int tn, int j) {
    gload_lds16((const char*)Wb + offB[j] + tn * 128 + sw16,
                dst + (j * 64 + w * 8) * 64);
  };
  auto dsA = [&](const unsigned short* buf, int mi, int kk) {
    const int row = wr * 128 + mi * 16 + lrow;
    const int g = (kk * 4 + lgrp) ^ (lrow & 7);
    return *reinterpret_cast<const bf16x8*>(&buf[row * 64 + g * 8]);
  };
  auto dsB = [&](const unsigned short* buf, int ni, int kk) {
    const int row = wc * 64 + ni * 16 + lrow;
    const int g = (kk * 4 + lgrp) ^ (lrow & 7);
    return *reinterpret_cast<const bf16x8*>(&buf[row * 64 + g * 8]);
  };

  // -------- prologue: stage tile 0, full drain ----------------------------
#pragma unroll
  for (int j = 0; j < 4; ++j) stageA(sA0, 0, j);
#pragma unroll
  for (int j = 0; j < 4; ++j) stageB(sB0, 0, j);
  asm volatile("s_waitcnt vmcnt(0)" ::: "memory");
  __builtin_amdgcn_s_barrier();
  MEMFENCE;

  // -------- main loop: 4 phases per K-tile --------------------------------
  for (int t = 0; t < T; ++t) {
    const unsigned short* da = (t & 1) ? sA1 : sA0;
    const unsigned short* db = (t & 1) ? sB1 : sB0;
    unsigned short* na = (t & 1) ? sA0 : sA1;
    unsigned short* nb = (t & 1) ? sB0 : sB1;
    const bool pf = (t + 1 < T);
    bf16x8 bfr[4][2];

#pragma unroll
    for (int q = 0; q < 4; ++q) {
      if (q == 0) {
#pragma unroll
        for (int ni = 0; ni < 4; ++ni) {
          bfr[ni][0] = dsB(db, ni, 0);
          bfr[ni][1] = dsB(db, ni, 1);
        }
      }
      bf16x8 a00 = dsA(da, 2 * q, 0);
      bf16x8 a01 = dsA(da, 2 * q, 1);
      bf16x8 a10 = dsA(da, 2 * q + 1, 0);
      bf16x8 a11 = dsA(da, 2 * q + 1, 1);

      if (q == 0 && pf) {
        stageA(na, t + 1, 0); stageA(na, t + 1, 1);
        stageB(nb, t + 1, 0); stageB(nb, t + 1, 1);
      }
      if (q == 1 && pf) {
        stageA(na, t + 1, 2); stageA(na, t + 1, 3);
        stageB(nb, t + 1, 2); stageB(nb, t + 1, 3);
      }

      MEMFENCE;
      __builtin_amdgcn_s_barrier();
      asm volatile("s_waitcnt lgkmcnt(0)" ::: "memory");
      __builtin_amdgcn_s_setprio(1);
#pragma unroll
      for (int ni = 0; ni < 4; ++ni) {
        acc[2 * q][ni] = __builtin_amdgcn_mfma_f32_16x16x32_bf16(
            a00, bfr[ni][0], acc[2 * q][ni], 0, 0, 0);
        acc[2 * q][ni] = __builtin_amdgcn_mfma_f32_16x16x32_bf16(
            a01, bfr[ni][1], acc[2 * q][ni], 0, 0, 0);
        acc[2 * q + 1][ni] = __builtin_amdgcn_mfma_f32_16x16x32_bf16(
            a10, bfr[ni][0], acc[2 * q + 1][ni], 0, 0, 0);
        acc[2 * q + 1][ni] = __builtin_amdgcn_mfma_f32_16x16x32_bf16(
            a11, bfr[ni][1], acc[2 * q + 1][ni], 0, 0, 0);
      }
      __builtin_amdgcn_s_setprio(0);
      if (q == 3) asm volatile("s_waitcnt vmcnt(0)" ::: "memory");
      MEMFENCE;
      __builtin_amdgcn_s_barrier();
      MEMFENCE;
    }
  }

  // -------- epilogue: bias + relu + residual (+mask) ----------------------
  float biasv[4];
#pragma unroll
  for (int ni = 0; ni < 4; ++ni)
    biasv[ni] = bias[col0 + wc * 64 + ni * 16 + lrow];

#pragma unroll
  for (int mi = 0; mi < 8; ++mi) {
#pragma unroll
    for (int jj = 0; jj < 4; ++jj) {
      const int m = row0 + wr * 128 + mi * 16 + lgrp * 4 + jj;
      const size_t ro = (size_t)m * kD;
      float mk = 1.0f;
      if constexpr (IS_RELA) mk = masks[m];
#pragma unroll
      for (int ni = 0; ni < 4; ++ni) {
        const int col = col0 + wc * 64 + ni * 16 + lrow;
        float v = acc[mi][ni][jj] + biasv[ni];
        v = fmaxf(v, 0.0f) + resid[ro + col];
        if constexpr (IS_RELA) v *= mk;
        out[ro + col] = v;
      }
    }
  }
}

extern "C" void kernel_launch(void* const* d_in, const int* in_sizes, int n_in,
                              void* d_out, int out_size, void* d_ws,
                              size_t ws_size, hipStream_t stream) {
  (void)in_sizes; (void)n_in; (void)out_size; (void)ws_size;
  const float* obj = (const float*)d_in[0];
  const float* attr = (const float*)d_in[1];
  const float* rela = (const float*)d_in[2];
  const int* edges = (const int*)d_in[3];
  const float* masks = (const float*)d_in[4];
  const float* W_attr = (const float*)d_in[5];
  const float* b_attr = (const float*)d_in[6];
  const float* W_rela = (const float*)d_in[7];
  const float* b_rela = (const float*)d_in[8];

  float* out0 = (float*)d_out;
  float* out1 = out0 + (size_t)kB * kN * kD;
  float* out2 = out1 + (size_t)kB * kN * kD;

  hipMemcpyAsync(out0, obj, (size_t)kB * kN * kD * sizeof(float),
                 hipMemcpyDeviceToDevice, stream);

  constexpr size_t nObj = (size_t)kB * kN * kD;
  constexpr size_t nRela = (size_t)kB * kR * kD;
  constexpr size_t nWa = (size_t)kD * 2 * kD;
  constexpr size_t nWr = (size_t)kD * 3 * kD;

  unsigned short* objb = (unsigned short*)d_ws;
  unsigned short* attrb = objb + nObj;
  unsigned short* relab = attrb + nObj;
  unsigned short* wab = relab + nRela;
  unsigned short* wrb = wab + nWa;

  auto cvt = [&](const float* in, unsigned short* o, size_t n) {
    const int n8 = (int)(n / 8);
    const int blocks = (n8 + 255) / 256 < 8192 ? (n8 + 255) / 256 : 8192;
    cvt_f32_bf16<<<blocks, 256, 0, stream>>>(in, o, n8);
  };
  cvt(obj, objb, nObj);
  cvt(attr, attrb, nObj);
  cvt(W_attr, wab, nWa);
  cvt(rela, relab, nRela);
  cvt(W_rela, wrb, nWr);

  constexpr int kSmem = 131072;
  hipFuncSetAttribute((const void*)gnn_gemm8<false, 2048, 8, 32>,
                      hipFuncAttributeMaxDynamicSharedMemorySize, kSmem);
  hipFuncSetAttribute((const void*)gnn_gemm8<true, 3072, 11, 256>,
                      hipFuncAttributeMaxDynamicSharedMemorySize, kSmem);

  // attr: 32 row-panels x 4 col-panels = 128 blocks
  gnn_gemm8<false, 2048, 8, 32><<<128, 512, kSmem, stream>>>(
      objb, attrb, wab, nullptr, nullptr, attr, b_attr, out1);
  // rela: 256 row-panels x 4 col-panels = 1024 blocks
  gnn_gemm8<true, 3072, 11, 256><<<1024, 512, kSmem, stream>>>(
      objb, relab, wrb, edges, masks, rela, b_rela, out2);
}

// Round 4
// 628.423 us; speedup vs baseline: 2.7298x; 1.4371x over previous
//
#include <hip/hip_runtime.h>
#include <hip/hip_bf16.h>

constexpr int kB = 32;
constexpr int kN = 256;
constexpr int kR = 2048;
constexpr int kD = 1024;

typedef short bf16x8 __attribute__((ext_vector_type(8)));
typedef float f32x4 __attribute__((ext_vector_type(4)));
typedef unsigned short u16x8 __attribute__((ext_vector_type(8)));

__device__ __forceinline__ unsigned short f2bf(float f) {
  union { __hip_bfloat16 h; unsigned short u; } cv;
  cv.h = __float2bfloat16(f);
  return cv.u;
}

__device__ __forceinline__ void gload_lds16(const void* g, void* l) {
  __builtin_amdgcn_global_load_lds(
      (const __attribute__((address_space(1))) unsigned int*)g,
      (__attribute__((address_space(3))) unsigned int*)l, 16, 0, 0);
}

#define FENCE asm volatile("" ::: "memory")
#define LGKM0 asm volatile("s_waitcnt lgkmcnt(0)" ::: "memory")
// lgkmcnt(0) before the barrier: all this wave's ds_reads retired -> after
// the barrier no wave can observe a slot overwrite racing its reads.
#define BARRIER \
  do { LGKM0; __builtin_amdgcn_s_barrier(); FENCE; } while (0)
#define WAITV(n) asm volatile("s_waitcnt vmcnt(" #n ")" ::: "memory")

// ---------------------------------------------------------------------------
// f32 -> bf16 pre-pass
// ---------------------------------------------------------------------------
__global__ void cvt_f32_bf16(const float* __restrict__ in,
                             unsigned short* __restrict__ out, int n8) {
  const int stride = gridDim.x * blockDim.x;
  for (int i = blockIdx.x * blockDim.x + threadIdx.x; i < n8; i += stride) {
    const float4 a = reinterpret_cast<const float4*>(in)[2 * i];
    const float4 b = reinterpret_cast<const float4*>(in)[2 * i + 1];
    u16x8 v;
    v[0] = f2bf(a.x); v[1] = f2bf(a.y); v[2] = f2bf(a.z); v[3] = f2bf(a.w);
    v[4] = f2bf(b.x); v[5] = f2bf(b.y); v[6] = f2bf(b.z); v[7] = f2bf(b.w);
    reinterpret_cast<u16x8*>(out)[i] = v;
  }
}

// ---------------------------------------------------------------------------
// 256x256 bf16 GEMM, BK=32, 4-slot LDS ring, counted-vmcnt pipeline (depth 3).
// C[m,d] = relu(sum_k A[m,k]*W[d,k] + bias[d]) + resid[m,d]  (*mask[m] rela)
// A row = concat of 1024-wide segments (32 BK-tiles each):
//   attr: [objb m, attrb m]                      (K=2048, T=64)
//   rela: [objb[subj], relab m, objb[obji]]      (K=3072, T=96)
// Slot = A[256 rows][32 k] (16 KB) + B[256 cols][32 k] (16 KB); 4 slots=128KB.
// Staging: 4 x global_load_lds(16B)/thread/tile, linear LDS dest; 16B-granule
// swizzle p = g ^ ((row>>1)&3) applied on the *global source* (rule #21);
// ds_read_b128 applies the same XOR -> 2 rows/bank-slot = conflict-free.
// Pipeline: issue tile t+3 right after tile t's barrier; wait vmcnt(8) keeps
// tiles t+1,t+2 in flight; vmcnt reaches 0 only in the 2-tile epilogue peel.
// ---------------------------------------------------------------------------
template <bool IS_RELA, int K_TOT, int LOG_RPB, int NPANEL>
__global__ __launch_bounds__(512, 2) void gnn_gemm_p(
    const unsigned short* __restrict__ objb,
    const unsigned short* __restrict__ seg1b,
    const unsigned short* __restrict__ Wb,
    const int* __restrict__ edges, const float* __restrict__ masks,
    const float* __restrict__ resid, const float* __restrict__ bias,
    float* __restrict__ out) {
  constexpr int T = K_TOT / 32;
  extern __shared__ unsigned short smem[];

  // XCD mapping: XCD x owns col panel (x>>1); (x&1) splits row panels.
  const int bid = blockIdx.x;
  const int x = bid & 7;
  const int col0 = (x >> 1) * 256;
  const int panel = (x & 1) * (NPANEL / 2) + (bid >> 3);
  const int row0 = panel * 256;

  const int tid = threadIdx.x;
  const int w = tid >> 6;   // wave 0..7
  const int l = tid & 63;

  // -------- staging geometry: load r in {0,1} covers LDS rows
  // (w*32 + r*16 + l>>2), physical granule l&3 (16B). Source granule
  // pre-swizzle: g = (l&3) ^ ((row>>1)&3) = (l&3) ^ ((l>>3)&3).
  const int sw = (((l & 3) ^ ((l >> 3) & 3)) << 4);  // bytes
  const char* pA0[2];
  const char* pA1[2];
  const char* pA2[2];
  const char* pB[2];
#pragma unroll
  for (int r = 0; r < 2; ++r) {
    const int rl = w * 32 + r * 16 + (l >> 2);
    const int m = row0 + rl;
    if constexpr (IS_RELA) {
      const int b = m >> LOG_RPB;
      const int ri = m & ((1 << LOG_RPB) - 1);
      const int2 e =
          *reinterpret_cast<const int2*>(&edges[((size_t)b * kR + ri) * 2]);
      pA0[r] = (const char*)(objb + (size_t)(b * kN + e.x) * kD);
      pA1[r] = (const char*)(seg1b + (size_t)m * kD);
      pA2[r] = (const char*)(objb + (size_t)(b * kN + e.y) * kD);
    } else {
      pA0[r] = (const char*)(objb + (size_t)m * kD);
      pA1[r] = (const char*)(seg1b + (size_t)m * kD);
      pA2[r] = pA0[r];
    }
    pB[r] = (const char*)(Wb + (size_t)(col0 + rl) * K_TOT);
  }

  // -------- compute identity: 2(M) x 4(N) waves, per-wave C = 128x64 -------
  const int wr = w >> 2;
  const int wc = w & 3;
  const int lrow = l & 15;
  const int lgrp = l >> 4;
  const int pgr = ((lgrp ^ ((lrow >> 1) & 3)) << 3);  // shorts

  f32x4 acc[8][4] = {};

  auto issue = [&](int tn, int slot) {
    unsigned short* ra = smem + slot * 16384;
    unsigned short* rb = ra + 8192;
    const int seg = tn >> 5;                // uniform
    const int ko = (tn & 31) << 6;          // bytes within segment row
    const size_t kb = (size_t)tn << 6;      // bytes within W row
#pragma unroll
    for (int r = 0; r < 2; ++r) {
      const char* srcA = pA0[r];
      if constexpr (IS_RELA) {
        if (seg == 1) srcA = pA1[r];
        else if (seg == 2) srcA = pA2[r];
      } else {
        if (seg == 1) srcA = pA1[r];
      }
      gload_lds16(srcA + ko + sw, ra + (w * 2 + r) * 512);
      gload_lds16(pB[r] + kb + sw, rb + (w * 2 + r) * 512);
    }
  };

  auto compute = [&](int slot) {
    const unsigned short* da = smem + slot * 16384;
    const unsigned short* db = da + 8192;
    bf16x8 bf[4], af[8];
#pragma unroll
    for (int ni = 0; ni < 4; ++ni)
      bf[ni] = *reinterpret_cast<const bf16x8*>(
          &db[(wc * 64 + ni * 16 + lrow) * 32 + pgr]);
#pragma unroll
    for (int mi = 0; mi < 8; ++mi)
      af[mi] = *reinterpret_cast<const bf16x8*>(
          &da[(wr * 128 + mi * 16 + lrow) * 32 + pgr]);
    __builtin_amdgcn_s_setprio(1);
#pragma unroll
    for (int mi = 0; mi < 8; ++mi)
#pragma unroll
      for (int ni = 0; ni < 4; ++ni)
        acc[mi][ni] = __builtin_amdgcn_mfma_f32_16x16x32_bf16(
            af[mi], bf[ni], acc[mi][ni], 0, 0, 0);
    __builtin_amdgcn_s_setprio(0);
  };

  // -------- prologue: 3 tiles in flight ------------------------------------
  issue(0, 0);
  issue(1, 1);
  issue(2, 2);

  // -------- main loop: T-4 tiles, static slots (T % 4 == 0) ----------------
  int t = 0;
#pragma unroll 1
  for (int it = 0; it < (T - 4) / 4; ++it, t += 4) {
    WAITV(8); BARRIER; issue(t + 3, 3); compute(0);
    WAITV(8); BARRIER; issue(t + 4, 0); compute(1);
    WAITV(8); BARRIER; issue(t + 5, 1); compute(2);
    WAITV(8); BARRIER; issue(t + 6, 2); compute(3);
  }
  // t == T-4
  WAITV(8); BARRIER; issue(T - 1, 3); compute(0);
  WAITV(8); BARRIER; compute(1);
  WAITV(4); BARRIER; compute(2);
  WAITV(0); BARRIER; compute(3);

  // -------- epilogue: bias + relu + residual (+mask) ----------------------
  float biasv[4];
#pragma unroll
  for (int ni = 0; ni < 4; ++ni)
    biasv[ni] = bias[col0 + wc * 64 + ni * 16 + lrow];

#pragma unroll
  for (int mi = 0; mi < 8; ++mi) {
#pragma unroll
    for (int jj = 0; jj < 4; ++jj) {
      const int m = row0 + wr * 128 + mi * 16 + lgrp * 4 + jj;
      const size_t ro = (size_t)m * kD;
      float mk = 1.0f;
      if constexpr (IS_RELA) mk = masks[m];
#pragma unroll
      for (int ni = 0; ni < 4; ++ni) {
        const int col = col0 + wc * 64 + ni * 16 + lrow;
        float v = acc[mi][ni][jj] + biasv[ni];
        v = fmaxf(v, 0.0f) + resid[ro + col];
        if constexpr (IS_RELA) v *= mk;
        out[ro + col] = v;
      }
    }
  }
}

extern "C" void kernel_launch(void* const* d_in, const int* in_sizes, int n_in,
                              void* d_out, int out_size, void* d_ws,
                              size_t ws_size, hipStream_t stream) {
  (void)in_sizes; (void)n_in; (void)out_size; (void)ws_size;
  const float* obj = (const float*)d_in[0];
  const float* attr = (const float*)d_in[1];
  const float* rela = (const float*)d_in[2];
  const int* edges = (const int*)d_in[3];
  const float* masks = (const float*)d_in[4];
  const float* W_attr = (const float*)d_in[5];
  const float* b_attr = (const float*)d_in[6];
  const float* W_rela = (const float*)d_in[7];
  const float* b_rela = (const float*)d_in[8];

  float* out0 = (float*)d_out;
  float* out1 = out0 + (size_t)kB * kN * kD;
  float* out2 = out1 + (size_t)kB * kN * kD;

  hipMemcpyAsync(out0, obj, (size_t)kB * kN * kD * sizeof(float),
                 hipMemcpyDeviceToDevice, stream);

  constexpr size_t nObj = (size_t)kB * kN * kD;
  constexpr size_t nRela = (size_t)kB * kR * kD;
  constexpr size_t nWa = (size_t)kD * 2 * kD;
  constexpr size_t nWr = (size_t)kD * 3 * kD;

  unsigned short* objb = (unsigned short*)d_ws;
  unsigned short* attrb = objb + nObj;
  unsigned short* relab = attrb + nObj;
  unsigned short* wab = relab + nRela;
  unsigned short* wrb = wab + nWa;

  auto cvt = [&](const float* in, unsigned short* o, size_t n) {
    const int n8 = (int)(n / 8);
    const int blocks = (n8 + 255) / 256 < 8192 ? (n8 + 255) / 256 : 8192;
    cvt_f32_bf16<<<blocks, 256, 0, stream>>>(in, o, n8);
  };
  cvt(obj, objb, nObj);
  cvt(attr, attrb, nObj);
  cvt(W_attr, wab, nWa);
  cvt(rela, relab, nRela);
  cvt(W_rela, wrb, nWr);

  constexpr int kSmem = 131072;
  hipFuncSetAttribute((const void*)gnn_gemm_p<false, 2048, 8, 32>,
                      hipFuncAttributeMaxDynamicSharedMemorySize, kSmem);
  hipFuncSetAttribute((const void*)gnn_gemm_p<true, 3072, 11, 256>,
                      hipFuncAttributeMaxDynamicSharedMemorySize, kSmem);

  // attr: 32 row-panels x 4 col-panels = 128 blocks
  gnn_gemm_p<false, 2048, 8, 32><<<128, 512, kSmem, stream>>>(
      objb, attrb, wab, nullptr, nullptr, attr, b_attr, out1);
  // rela: 256 row-panels x 4 col-panels = 1024 blocks
  gnn_gemm_p<true, 3072, 11, 256><<<1024, 512, kSmem, stream>>>(
      objb, relab, wrb, edges, masks, rela, b_rela, out2);
}

// Round 5
// 604.826 us; speedup vs baseline: 2.8363x; 1.0390x over previous
//
#include <hip/hip_runtime.h>
#include <hip/hip_bf16.h>

constexpr int kB = 32;
constexpr int kN = 256;
constexpr int kR = 2048;
constexpr int kD = 1024;

typedef short bf16x8 __attribute__((ext_vector_type(8)));
typedef float f32x4 __attribute__((ext_vector_type(4)));
typedef unsigned short u16x8 __attribute__((ext_vector_type(8)));

__device__ __forceinline__ unsigned short f2bf(float f) {
  union { __hip_bfloat16 h; unsigned short u; } cv;
  cv.h = __float2bfloat16(f);
  return cv.u;
}

__device__ __forceinline__ void gload_lds16(const void* g, void* l) {
  __builtin_amdgcn_global_load_lds(
      (const __attribute__((address_space(1))) unsigned int*)g,
      (__attribute__((address_space(3))) unsigned int*)l, 16, 0, 0);
}

#define FENCE asm volatile("" ::: "memory")
#define LGKM0 asm volatile("s_waitcnt lgkmcnt(0)" ::: "memory")
// lgkmcnt(0) + barrier: every wave's ds_reads of the slot about to be
// overwritten have retired before any wave issues the overwrite.
#define BARRIER \
  do { LGKM0; __builtin_amdgcn_s_barrier(); FENCE; } while (0)
#define WAITV(n) asm volatile("s_waitcnt vmcnt(" #n ")" ::: "memory")

// ---------------------------------------------------------------------------
// Fused f32 -> bf16 pre-pass for all 5 GEMM operands (one launch).
// ---------------------------------------------------------------------------
__global__ void cvt_all(const float* __restrict__ obj,
                        const float* __restrict__ attr,
                        const float* __restrict__ rela,
                        const float* __restrict__ wa,
                        const float* __restrict__ wr,
                        unsigned short* __restrict__ objb,
                        unsigned short* __restrict__ attrb,
                        unsigned short* __restrict__ relab,
                        unsigned short* __restrict__ wab,
                        unsigned short* __restrict__ wrb) {
  constexpr long n0 = (long)kB * kN * kD / 8;          // obj
  constexpr long c0 = n0;
  constexpr long c1 = c0 + n0;                          // attr
  constexpr long c2 = c1 + (long)kB * kR * kD / 8;      // rela
  constexpr long c3 = c2 + (long)kD * 2 * kD / 8;       // W_attr
  constexpr long c4 = c3 + (long)kD * 3 * kD / 8;       // W_rela
  const long stride = (long)gridDim.x * blockDim.x;
  for (long i = (long)blockIdx.x * blockDim.x + threadIdx.x; i < c4;
       i += stride) {
    const float* s;
    unsigned short* d;
    long j;
    if (i < c0)      { s = obj;  d = objb;  j = i; }
    else if (i < c1) { s = attr; d = attrb; j = i - c0; }
    else if (i < c2) { s = rela; d = relab; j = i - c1; }
    else if (i < c3) { s = wa;   d = wab;   j = i - c2; }
    else             { s = wr;   d = wrb;   j = i - c3; }
    const float4 a = reinterpret_cast<const float4*>(s)[2 * j];
    const float4 b = reinterpret_cast<const float4*>(s)[2 * j + 1];
    u16x8 v;
    v[0] = f2bf(a.x); v[1] = f2bf(a.y); v[2] = f2bf(a.z); v[3] = f2bf(a.w);
    v[4] = f2bf(b.x); v[5] = f2bf(b.y); v[6] = f2bf(b.z); v[7] = f2bf(b.w);
    reinterpret_cast<u16x8*>(d)[j] = v;
  }
}

// ---------------------------------------------------------------------------
// 256x256 bf16 GEMM, BK=32, 4-slot LDS ring, counted-vmcnt (depth 3),
// register-double-buffered B fragments, JIT A fragments (read/MFMA interleave).
// C[m,d] = relu(sum_k A[m,k]*W[d,k] + bias[d]) + resid[m,d]  (*mask[m] rela)
// A row = concat of 1024-wide segments (32 BK-tiles each):
//   attr: [objb m, attrb m]                      (K=2048, T=64)
//   rela: [objb[subj], relab m, objb[obji]]      (K=3072, T=96)
// Iteration i: WAITV(4) [tile i+1 resident] -> BARRIER [WAR safety via lgkm0]
// -> issue tile i+3 (slot (i+3)&3) -> read B(i+1) frags into set (i+1)&1
// -> MFMA tile i: 8x { 1 ds_read A-frag; 4 MFMA with Bf[i&1] }.
// MFMA(i) depends only on last iteration's B-reads and this phase's A-reads,
// which the compiler interleaves via fine lgkmcnt -> LDS and MFMA pipes
// overlap within each wave; vmcnt never drains to 0 until the tail.
// ---------------------------------------------------------------------------
template <bool IS_RELA, int K_TOT, int LOG_RPB, int NPANEL>
__global__ __launch_bounds__(512, 2) void gnn_gemm_p(
    const unsigned short* __restrict__ objb,
    const unsigned short* __restrict__ seg1b,
    const unsigned short* __restrict__ Wb,
    const int* __restrict__ edges, const float* __restrict__ masks,
    const float* __restrict__ resid, const float* __restrict__ bias,
    float* __restrict__ out) {
  constexpr int T = K_TOT / 32;
  extern __shared__ unsigned short smem[];

  // XCD mapping: XCD x owns col panel (x>>1); (x&1) splits row panels.
  const int bid = blockIdx.x;
  const int x = bid & 7;
  const int col0 = (x >> 1) * 256;
  const int panel = (x & 1) * (NPANEL / 2) + (bid >> 3);
  const int row0 = panel * 256;

  const int tid = threadIdx.x;
  const int w = tid >> 6;   // wave 0..7
  const int l = tid & 63;

  // -------- staging geometry (identical to verified round-4 layout) -------
  // load r in {0,1} covers LDS rows (w*32 + r*16 + l>>2), granule l&3 (16B);
  // source granule pre-swizzle g = (l&3) ^ ((l>>3)&3)  (rule #21).
  const int sw = (((l & 3) ^ ((l >> 3) & 3)) << 4);  // bytes
  uint32_t oA0[2], oA1[2], oA2[2], oB[2];
#pragma unroll
  for (int r = 0; r < 2; ++r) {
    const int rl = w * 32 + r * 16 + (l >> 2);
    const int m = row0 + rl;
    if constexpr (IS_RELA) {
      const int b = m >> LOG_RPB;
      const int ri = m & ((1 << LOG_RPB) - 1);
      const int2 e =
          *reinterpret_cast<const int2*>(&edges[((size_t)b * kR + ri) * 2]);
      oA0[r] = (uint32_t)((b * kN + e.x) * kD) * 2u;
      oA1[r] = (uint32_t)((size_t)m * kD * 2);
      oA2[r] = (uint32_t)((b * kN + e.y) * kD) * 2u;
    } else {
      oA0[r] = (uint32_t)((size_t)m * kD * 2);
      oA1[r] = oA0[r];
      oA2[r] = 0;
    }
    oB[r] = (uint32_t)((size_t)(col0 + rl) * K_TOT * 2);
  }

  // -------- compute identity: 2(M) x 4(N) waves, per-wave C = 128x64 ------
  const int wr = w >> 2;
  const int wc = w & 3;
  const int lrow = l & 15;
  const int lgrp = l >> 4;
  const int pgr = ((lgrp ^ ((lrow >> 1) & 3)) << 3);  // shorts

  f32x4 acc[8][4] = {};
  bf16x8 Bf0[4], Bf1[4];

  auto issue = [&](int tn, int slot) {
    unsigned short* ra = smem + slot * 16384;
    unsigned short* rb = ra + 8192;
    const int seg = tn >> 5;                 // wave-uniform
    const uint32_t ko = (uint32_t)(tn & 31) << 6;  // bytes in segment row
    const uint32_t kb = (uint32_t)tn << 6;         // bytes in W row
#pragma unroll
    for (int r = 0; r < 2; ++r) {
      const char* srcA;
      if constexpr (IS_RELA) {
        srcA = (seg == 1) ? (const char*)seg1b + oA1[r]
                          : (const char*)objb + (seg == 0 ? oA0[r] : oA2[r]);
      } else {
        srcA = (seg == 0) ? (const char*)objb + oA0[r]
                          : (const char*)seg1b + oA1[r];
      }
      gload_lds16(srcA + ko + sw, ra + (w * 2 + r) * 512);
      gload_lds16((const char*)Wb + oB[r] + kb + sw, rb + (w * 2 + r) * 512);
    }
  };

#define READB(tn_slot, SET)                                                \
  {                                                                        \
    const unsigned short* db_ = smem + (tn_slot) * 16384 + 8192;           \
    _Pragma("unroll")                                                      \
    for (int ni = 0; ni < 4; ++ni)                                         \
      Bf##SET[ni] = *reinterpret_cast<const bf16x8*>(                      \
          &db_[(wc * 64 + ni * 16 + lrow) * 32 + pgr]);                    \
  }

#define COMPUTE(slot, SET)                                                 \
  {                                                                        \
    const unsigned short* da_ = smem + (slot) * 16384;                     \
    _Pragma("unroll")                                                      \
    for (int mi = 0; mi < 8; ++mi) {                                       \
      bf16x8 a_ = *reinterpret_cast<const bf16x8*>(                        \
          &da_[(wr * 128 + mi * 16 + lrow) * 32 + pgr]);                   \
      _Pragma("unroll")                                                    \
      for (int ni = 0; ni < 4; ++ni)                                       \
        acc[mi][ni] = __builtin_amdgcn_mfma_f32_16x16x32_bf16(             \
            a_, Bf##SET[ni], acc[mi][ni], 0, 0, 0);                        \
    }                                                                      \
  }

// STEP for tile i: SLOT=(i)&3, MFMA uses Bf[SETM=(i)&1], reads B(i+1) into
// the other set from slot (i+1)&3; issues tile i+3 into slot (i+3)&3.
#define STEP(i, SLOT, DO_ISSUE, SETM, SETR, WN)                            \
  WAITV(WN);                                                               \
  BARRIER;                                                                 \
  if (DO_ISSUE) issue((i) + 3, ((SLOT) + 3) & 3);                          \
  READB(((SLOT) + 1) & 3, SETR);                                           \
  COMPUTE(SLOT, SETM);

  // -------- prologue: 3 tiles in flight, B(0) fragments loaded ------------
  issue(0, 0);
  issue(1, 1);
  issue(2, 2);
  WAITV(8);  // tile 0 landed
  BARRIER;
  READB(0, 0);

  // -------- main loop: i = 0 .. T-5, unrolled by 4 (T % 4 == 0) -----------
  int i = 0;
#pragma unroll 1
  for (int it = 0; it < (T - 4) / 4; ++it, i += 4) {
    STEP(i + 0, 0, true, 0, 1, 4);
    STEP(i + 1, 1, true, 1, 0, 4);
    STEP(i + 2, 2, true, 0, 1, 4);
    STEP(i + 3, 3, true, 1, 0, 4);
  }
  // -------- tail: i = T-4 .. T-1 (T-4 is even; slots 0,1,2,3) -------------
  STEP(T - 4, 0, true, 0, 1, 4);    // last issue: tile T-1 -> slot 3
  STEP(T - 3, 1, false, 1, 0, 4);   // tile T-2 resident after wait
  STEP(T - 2, 2, false, 0, 1, 0);   // tile T-1 resident; reads B(T-1)
  COMPUTE(3, 1);                     // tile T-1 (no wait/barrier needed)

#undef STEP
#undef COMPUTE
#undef READB

  // -------- epilogue: bias + relu + residual (+mask) ----------------------
  float biasv[4];
#pragma unroll
  for (int ni = 0; ni < 4; ++ni)
    biasv[ni] = bias[col0 + wc * 64 + ni * 16 + lrow];

#pragma unroll
  for (int mi = 0; mi < 8; ++mi) {
#pragma unroll
    for (int jj = 0; jj < 4; ++jj) {
      const int m = row0 + wr * 128 + mi * 16 + lgrp * 4 + jj;
      const size_t ro = (size_t)m * kD;
      float mk = 1.0f;
      if constexpr (IS_RELA) mk = masks[m];
#pragma unroll
      for (int ni = 0; ni < 4; ++ni) {
        const int col = col0 + wc * 64 + ni * 16 + lrow;
        float v = acc[mi][ni][jj] + biasv[ni];
        v = fmaxf(v, 0.0f) + resid[ro + col];
        if constexpr (IS_RELA) v *= mk;
        out[ro + col] = v;
      }
    }
  }
}

extern "C" void kernel_launch(void* const* d_in, const int* in_sizes, int n_in,
                              void* d_out, int out_size, void* d_ws,
                              size_t ws_size, hipStream_t stream) {
  (void)in_sizes; (void)n_in; (void)out_size; (void)ws_size;
  const float* obj = (const float*)d_in[0];
  const float* attr = (const float*)d_in[1];
  const float* rela = (const float*)d_in[2];
  const int* edges = (const int*)d_in[3];
  const float* masks = (const float*)d_in[4];
  const float* W_attr = (const float*)d_in[5];
  const float* b_attr = (const float*)d_in[6];
  const float* W_rela = (const float*)d_in[7];
  const float* b_rela = (const float*)d_in[8];

  float* out0 = (float*)d_out;
  float* out1 = out0 + (size_t)kB * kN * kD;
  float* out2 = out1 + (size_t)kB * kN * kD;

  hipMemcpyAsync(out0, obj, (size_t)kB * kN * kD * sizeof(float),
                 hipMemcpyDeviceToDevice, stream);

  constexpr size_t nObj = (size_t)kB * kN * kD;
  constexpr size_t nRela = (size_t)kB * kR * kD;
  constexpr size_t nWa = (size_t)kD * 2 * kD;

  unsigned short* objb = (unsigned short*)d_ws;
  unsigned short* attrb = objb + nObj;
  unsigned short* relab = attrb + nObj;
  unsigned short* wab = relab + nRela;
  unsigned short* wrb = wab + nWa;

  cvt_all<<<2048, 256, 0, stream>>>(obj, attr, rela, W_attr, W_rela, objb,
                                    attrb, relab, wab, wrb);

  constexpr int kSmem = 131072;
  hipFuncSetAttribute((const void*)gnn_gemm_p<false, 2048, 8, 32>,
                      hipFuncAttributeMaxDynamicSharedMemorySize, kSmem);
  hipFuncSetAttribute((const void*)gnn_gemm_p<true, 3072, 11, 256>,
                      hipFuncAttributeMaxDynamicSharedMemorySize, kSmem);

  // attr: 32 row-panels x 4 col-panels = 128 blocks
  gnn_gemm_p<false, 2048, 8, 32><<<128, 512, kSmem, stream>>>(
      objb, attrb, wab, nullptr, nullptr, attr, b_attr, out1);
  // rela: 256 row-panels x 4 col-panels = 1024 blocks
  gnn_gemm_p<true, 3072, 11, 256><<<1024, 512, kSmem, stream>>>(
      objb, relab, wrb, edges, masks, rela, b_rela, out2);
}

// Round 6
// 603.973 us; speedup vs baseline: 2.8403x; 1.0014x over previous
//
#include <hip/hip_runtime.h>
#include <hip/hip_bf16.h>

constexpr int kB = 32;
constexpr int kN = 256;
constexpr int kR = 2048;
constexpr int kD = 1024;

typedef short bf16x8 __attribute__((ext_vector_type(8)));
typedef float f32x4 __attribute__((ext_vector_type(4)));
typedef unsigned short u16x8 __attribute__((ext_vector_type(8)));

__device__ __forceinline__ unsigned short f2bf(float f) {
  union { __hip_bfloat16 h; unsigned short u; } cv;
  cv.h = __float2bfloat16(f);
  return cv.u;
}

__device__ __forceinline__ void gload_lds16(const void* g, void* l) {
  __builtin_amdgcn_global_load_lds(
      (const __attribute__((address_space(1))) unsigned int*)g,
      (__attribute__((address_space(3))) unsigned int*)l, 16, 0, 0);
}

#define FENCE asm volatile("" ::: "memory")
#define LGKM0 asm volatile("s_waitcnt lgkmcnt(0)" ::: "memory")
// lgkmcnt(0)+barrier: every wave's ds_reads of a slot retired before any
// wave can issue an overwrite of it after the barrier (WAR safety).
#define BARRIER \
  do { LGKM0; __builtin_amdgcn_s_barrier(); FENCE; } while (0)
#define WAITV(n) asm volatile("s_waitcnt vmcnt(" #n ")" ::: "memory")

// ---------------------------------------------------------------------------
// Fused f32->bf16 pre-pass for all 5 GEMM operands + out0 passthrough copy.
// ---------------------------------------------------------------------------
__global__ void cvt_all(const float* __restrict__ obj,
                        const float* __restrict__ attr,
                        const float* __restrict__ rela,
                        const float* __restrict__ wa,
                        const float* __restrict__ wr,
                        unsigned short* __restrict__ objb,
                        unsigned short* __restrict__ attrb,
                        unsigned short* __restrict__ relab,
                        unsigned short* __restrict__ wab,
                        unsigned short* __restrict__ wrb,
                        float* __restrict__ out0) {
  constexpr long n0 = (long)kB * kN * kD / 8;          // obj
  constexpr long c0 = n0;
  constexpr long c1 = c0 + n0;                          // attr
  constexpr long c2 = c1 + (long)kB * kR * kD / 8;      // rela
  constexpr long c3 = c2 + (long)kD * 2 * kD / 8;       // W_attr
  constexpr long c4 = c3 + (long)kD * 3 * kD / 8;       // W_rela
  const long stride = (long)gridDim.x * blockDim.x;
  for (long i = (long)blockIdx.x * blockDim.x + threadIdx.x; i < c4;
       i += stride) {
    const float* s;
    unsigned short* d;
    long j;
    bool isobj = false;
    if (i < c0)      { s = obj;  d = objb;  j = i; isobj = true; }
    else if (i < c1) { s = attr; d = attrb; j = i - c0; }
    else if (i < c2) { s = rela; d = relab; j = i - c1; }
    else if (i < c3) { s = wa;   d = wab;   j = i - c2; }
    else             { s = wr;   d = wrb;   j = i - c3; }
    const float4 a = reinterpret_cast<const float4*>(s)[2 * j];
    const float4 b = reinterpret_cast<const float4*>(s)[2 * j + 1];
    if (isobj) {  // out0 = obj passthrough, fused with the convert read
      reinterpret_cast<float4*>(out0)[2 * j] = a;
      reinterpret_cast<float4*>(out0)[2 * j + 1] = b;
    }
    u16x8 v;
    v[0] = f2bf(a.x); v[1] = f2bf(a.y); v[2] = f2bf(a.z); v[3] = f2bf(a.w);
    v[4] = f2bf(b.x); v[5] = f2bf(b.y); v[6] = f2bf(b.z); v[7] = f2bf(b.w);
    reinterpret_cast<u16x8*>(d)[j] = v;
  }
}

// ---------------------------------------------------------------------------
// 256x256 bf16 GEMM body, BK=32, 4-slot LDS ring, counted-vmcnt depth 3,
// m201-style phase sandwich: per tile 2 phases of
//   {ds_read frags || issue stage(t+3)} -> barrier -> lgkm0 ->
//   setprio(1) 16 MFMA setprio(0) -> barrier
// A-stage issued in P0, B-stage in P1 -> steady-state vmcnt(8) (2 tiles in
// flight); vmcnt drains only in the last 3 tiles.
// C[m,d] = relu(sum_k A[m,k]*W[d,k] + bias[d]) + resid[m,d]  (*mask[m] rela)
// A row = concat of 1024-wide segments (32 BK-tiles each):
//   attr: [objb m, attrb m]                      (K=2048, T=64)
//   rela: [objb[subj], relab m, objb[obji]]      (K=3072, T=96)
// LDS slot = A[256][32] + B[256][32] bf16 = 32 KB; 4 slots = 128 KB.
// Staging/read geometry identical to round-4/5 (verified, 0 bank conflicts).
// ---------------------------------------------------------------------------
template <bool IS_RELA, int K_TOT, int LOG_RPB, int NPANEL>
__device__ __forceinline__ void gemm_body(
    int bid, unsigned short* smem,
    const unsigned short* __restrict__ objb,
    const unsigned short* __restrict__ seg1b,
    const unsigned short* __restrict__ Wb,
    const int* __restrict__ edges, const float* __restrict__ masks,
    const float* __restrict__ resid, const float* __restrict__ bias,
    float* __restrict__ out) {
  constexpr int T = K_TOT / 32;

  // XCD mapping: XCD x owns col panel (x>>1); (x&1) splits row panels.
  const int x = bid & 7;
  const int col0 = (x >> 1) * 256;
  const int panel = (x & 1) * (NPANEL / 2) + (bid >> 3);
  const int row0 = panel * 256;

  const int tid = threadIdx.x;
  const int w = tid >> 6;   // wave 0..7
  const int l = tid & 63;

  // staging: load r in {0,1} covers LDS rows (w*32 + r*16 + l>>2), granule
  // l&3 (16B); source granule pre-swizzle g = (l&3) ^ ((l>>3)&3) (rule #21).
  const int sw = (((l & 3) ^ ((l >> 3) & 3)) << 4);  // bytes
  uint32_t oA0[2], oA1[2], oA2[2], oB[2];
#pragma unroll
  for (int r = 0; r < 2; ++r) {
    const int rl = w * 32 + r * 16 + (l >> 2);
    const int m = row0 + rl;
    if constexpr (IS_RELA) {
      const int b = m >> LOG_RPB;
      const int ri = m & ((1 << LOG_RPB) - 1);
      const int2 e =
          *reinterpret_cast<const int2*>(&edges[((size_t)b * kR + ri) * 2]);
      oA0[r] = (uint32_t)((b * kN + e.x) * kD) * 2u;
      oA1[r] = (uint32_t)((size_t)m * kD * 2);
      oA2[r] = (uint32_t)((b * kN + e.y) * kD) * 2u;
    } else {
      oA0[r] = (uint32_t)((size_t)m * kD * 2);
      oA1[r] = oA0[r];
      oA2[r] = 0;
    }
    oB[r] = (uint32_t)((size_t)(col0 + rl) * K_TOT * 2);
  }

  const int wr = w >> 2;
  const int wc = w & 3;
  const int lrow = l & 15;
  const int lgrp = l >> 4;
  const int pgr = ((lgrp ^ ((lrow >> 1) & 3)) << 3);  // shorts

  f32x4 acc[8][4] = {};

  auto issueA = [&](int tn, int slot) {
    unsigned short* ra = smem + slot * 16384;
    const int seg = tn >> 5;                       // wave-uniform
    const uint32_t ko = (uint32_t)(tn & 31) << 6;  // bytes in segment row
#pragma unroll
    for (int r = 0; r < 2; ++r) {
      const char* srcA;
      if constexpr (IS_RELA) {
        srcA = (seg == 1) ? (const char*)seg1b + oA1[r]
                          : (const char*)objb + (seg == 0 ? oA0[r] : oA2[r]);
      } else {
        srcA = (seg == 0) ? (const char*)objb + oA0[r]
                          : (const char*)seg1b + oA1[r];
      }
      gload_lds16(srcA + ko + sw, ra + (w * 2 + r) * 512);
    }
  };
  auto issueB = [&](int tn, int slot) {
    unsigned short* rb = smem + slot * 16384 + 8192;
    const uint32_t kb2 = (uint32_t)tn << 6;        // bytes in W row
#pragma unroll
    for (int r = 0; r < 2; ++r)
      gload_lds16((const char*)Wb + oB[r] + kb2 + sw, rb + (w * 2 + r) * 512);
  };

// STEP for tile i in slot SLOT: 2-phase sandwich. WTOK = vmcnt token for P1.
#define STEP(i, SLOT, DO_ISSUE, WTOK)                                      \
  {                                                                        \
    const unsigned short* da_ = smem + (SLOT) * 16384;                     \
    const unsigned short* db_ = da_ + 8192;                                \
    bf16x8 Bf[4], Af[4];                                                   \
    _Pragma("unroll")                                                      \
    for (int ni = 0; ni < 4; ++ni)                                         \
      Bf[ni] = *reinterpret_cast<const bf16x8*>(                           \
          &db_[(wc * 64 + ni * 16 + lrow) * 32 + pgr]);                    \
    _Pragma("unroll")                                                      \
    for (int mi = 0; mi < 4; ++mi)                                         \
      Af[mi] = *reinterpret_cast<const bf16x8*>(                           \
          &da_[(wr * 128 + mi * 16 + lrow) * 32 + pgr]);                   \
    if (DO_ISSUE) issueA((i) + 3, ((SLOT) + 3) & 3);                       \
    BARRIER;                                                               \
    __builtin_amdgcn_s_setprio(1);                                         \
    _Pragma("unroll")                                                      \
    for (int mi = 0; mi < 4; ++mi)                                         \
      _Pragma("unroll")                                                    \
      for (int ni = 0; ni < 4; ++ni)                                       \
        acc[mi][ni] = __builtin_amdgcn_mfma_f32_16x16x32_bf16(             \
            Af[mi], Bf[ni], acc[mi][ni], 0, 0, 0);                         \
    __builtin_amdgcn_s_setprio(0);                                         \
    __builtin_amdgcn_s_barrier();                                          \
    FENCE;                                                                 \
    _Pragma("unroll")                                                      \
    for (int mi = 0; mi < 4; ++mi)                                         \
      Af[mi] = *reinterpret_cast<const bf16x8*>(                           \
          &da_[(wr * 128 + (mi + 4) * 16 + lrow) * 32 + pgr]);             \
    if (DO_ISSUE) issueB((i) + 3, ((SLOT) + 3) & 3);                       \
    WAITV(WTOK);                                                           \
    BARRIER;                                                               \
    __builtin_amdgcn_s_setprio(1);                                         \
    _Pragma("unroll")                                                      \
    for (int mi = 0; mi < 4; ++mi)                                         \
      _Pragma("unroll")                                                    \
      for (int ni = 0; ni < 4; ++ni)                                       \
        acc[mi + 4][ni] = __builtin_amdgcn_mfma_f32_16x16x32_bf16(         \
            Af[mi], Bf[ni], acc[mi + 4][ni], 0, 0, 0);                     \
    __builtin_amdgcn_s_setprio(0);                                         \
    __builtin_amdgcn_s_barrier();                                          \
    FENCE;                                                                 \
  }

  // prologue: 3 tiles in flight (A+B each = 12 loads); tile 0 resident
  issueA(0, 0); issueB(0, 0);
  issueA(1, 1); issueB(1, 1);
  issueA(2, 2); issueB(2, 2);
  WAITV(8);
  __builtin_amdgcn_s_barrier();
  FENCE;

  // main loop: t = 0 .. T-5 (T % 4 == 0)
#pragma unroll 1
  for (int it = 0; it < (T - 4) / 4; ++it) {
    const int t = it * 4;
    STEP(t + 0, 0, true, 8);
    STEP(t + 1, 1, true, 8);
    STEP(t + 2, 2, true, 8);
    STEP(t + 3, 3, true, 8);
  }
  // tail: tiles T-4 .. T-1
  STEP(T - 4, 0, true, 8);    // last issue: tile T-1 -> slot 3
  STEP(T - 3, 1, false, 4);   // retire tile T-2's loads
  STEP(T - 2, 2, false, 0);   // retire tile T-1's loads
  STEP(T - 1, 3, false, 0);

#undef STEP

  // epilogue: bias + relu + residual (+mask)
  float biasv[4];
#pragma unroll
  for (int ni = 0; ni < 4; ++ni)
    biasv[ni] = bias[col0 + wc * 64 + ni * 16 + lrow];

#pragma unroll
  for (int mi = 0; mi < 8; ++mi) {
#pragma unroll
    for (int jj = 0; jj < 4; ++jj) {
      const int m = row0 + wr * 128 + mi * 16 + lgrp * 4 + jj;
      const size_t ro = (size_t)m * kD;
      float mk = 1.0f;
      if constexpr (IS_RELA) mk = masks[m];
#pragma unroll
      for (int ni = 0; ni < 4; ++ni) {
        const int col = col0 + wc * 64 + ni * 16 + lrow;
        float v = acc[mi][ni][jj] + biasv[ni];
        v = fmaxf(v, 0.0f) + resid[ro + col];
        if constexpr (IS_RELA) v *= mk;
        out[ro + col] = v;
      }
    }
  }
}

// ---------------------------------------------------------------------------
// Fused launch: blocks 0..1023 = rela GEMM, 1024..1151 = attr GEMM.
// Rela first so the small attr grid fills the tail as CUs drain.
// ---------------------------------------------------------------------------
__global__ __launch_bounds__(512, 2) void gnn_fused(
    const unsigned short* __restrict__ objb,
    const unsigned short* __restrict__ attrb,
    const unsigned short* __restrict__ relab,
    const unsigned short* __restrict__ wab,
    const unsigned short* __restrict__ wrb,
    const int* __restrict__ edges, const float* __restrict__ masks,
    const float* __restrict__ attr, const float* __restrict__ rela,
    const float* __restrict__ b_attr, const float* __restrict__ b_rela,
    float* __restrict__ out1, float* __restrict__ out2) {
  extern __shared__ unsigned short smem[];
  const int bid = blockIdx.x;
  if (bid < 1024) {
    gemm_body<true, 3072, 11, 256>(bid, smem, objb, relab, wrb, edges, masks,
                                   rela, b_rela, out2);
  } else {
    gemm_body<false, 2048, 8, 32>(bid - 1024, smem, objb, attrb, wab, nullptr,
                                  nullptr, attr, b_attr, out1);
  }
}

extern "C" void kernel_launch(void* const* d_in, const int* in_sizes, int n_in,
                              void* d_out, int out_size, void* d_ws,
                              size_t ws_size, hipStream_t stream) {
  (void)in_sizes; (void)n_in; (void)out_size; (void)ws_size;
  const float* obj = (const float*)d_in[0];
  const float* attr = (const float*)d_in[1];
  const float* rela = (const float*)d_in[2];
  const int* edges = (const int*)d_in[3];
  const float* masks = (const float*)d_in[4];
  const float* W_attr = (const float*)d_in[5];
  const float* b_attr = (const float*)d_in[6];
  const float* W_rela = (const float*)d_in[7];
  const float* b_rela = (const float*)d_in[8];

  float* out0 = (float*)d_out;
  float* out1 = out0 + (size_t)kB * kN * kD;
  float* out2 = out1 + (size_t)kB * kN * kD;

  constexpr size_t nObj = (size_t)kB * kN * kD;
  constexpr size_t nRela = (size_t)kB * kR * kD;
  constexpr size_t nWa = (size_t)kD * 2 * kD;

  unsigned short* objb = (unsigned short*)d_ws;
  unsigned short* attrb = objb + nObj;
  unsigned short* relab = attrb + nObj;
  unsigned short* wab = relab + nRela;
  unsigned short* wrb = wab + nWa;

  cvt_all<<<2048, 256, 0, stream>>>(obj, attr, rela, W_attr, W_rela, objb,
                                    attrb, relab, wab, wrb, out0);

  constexpr int kSmem = 131072;
  hipFuncSetAttribute((const void*)gnn_fused,
                      hipFuncAttributeMaxDynamicSharedMemorySize, kSmem);
  gnn_fused<<<1152, 512, kSmem, stream>>>(objb, attrb, relab, wab, wrb, edges,
                                          masks, attr, rela, b_attr, b_rela,
                                          out1, out2);
}

// Round 7
// 584.891 us; speedup vs baseline: 2.9330x; 1.0326x over previous
//
#include <hip/hip_runtime.h>
#include <hip/hip_bf16.h>

constexpr int kB = 32;
constexpr int kN = 256;
constexpr int kR = 2048;
constexpr int kD = 1024;

typedef short bf16x8 __attribute__((ext_vector_type(8)));
typedef float f32x4 __attribute__((ext_vector_type(4)));
typedef unsigned short u16x8 __attribute__((ext_vector_type(8)));

__device__ __forceinline__ unsigned short f2bf(float f) {
  union { __hip_bfloat16 h; unsigned short u; } cv;
  cv.h = __float2bfloat16(f);
  return cv.u;
}

__device__ __forceinline__ void gload_lds16(const void* g, void* l) {
  __builtin_amdgcn_global_load_lds(
      (const __attribute__((address_space(1))) unsigned int*)g,
      (__attribute__((address_space(3))) unsigned int*)l, 16, 0, 0);
}

#define FENCE asm volatile("" ::: "memory")
#define WAITV(n) asm volatile("s_waitcnt vmcnt(" #n ")" ::: "memory")
#define LGKM(n) asm volatile("s_waitcnt lgkmcnt(" #n ")" ::: "memory")

// ---------------------------------------------------------------------------
// Fused f32->bf16 pre-pass for all 5 GEMM operands + out0 passthrough copy.
// ---------------------------------------------------------------------------
__global__ void cvt_all(const float* __restrict__ obj,
                        const float* __restrict__ attr,
                        const float* __restrict__ rela,
                        const float* __restrict__ wa,
                        const float* __restrict__ wr,
                        unsigned short* __restrict__ objb,
                        unsigned short* __restrict__ attrb,
                        unsigned short* __restrict__ relab,
                        unsigned short* __restrict__ wab,
                        unsigned short* __restrict__ wrb,
                        float* __restrict__ out0) {
  constexpr long n0 = (long)kB * kN * kD / 8;          // obj
  constexpr long c0 = n0;
  constexpr long c1 = c0 + n0;                          // attr
  constexpr long c2 = c1 + (long)kB * kR * kD / 8;      // rela
  constexpr long c3 = c2 + (long)kD * 2 * kD / 8;       // W_attr
  constexpr long c4 = c3 + (long)kD * 3 * kD / 8;       // W_rela
  const long stride = (long)gridDim.x * blockDim.x;
  for (long i = (long)blockIdx.x * blockDim.x + threadIdx.x; i < c4;
       i += stride) {
    const float* s;
    unsigned short* d;
    long j;
    bool isobj = false;
    if (i < c0)      { s = obj;  d = objb;  j = i; isobj = true; }
    else if (i < c1) { s = attr; d = attrb; j = i - c0; }
    else if (i < c2) { s = rela; d = relab; j = i - c1; }
    else if (i < c3) { s = wa;   d = wab;   j = i - c2; }
    else             { s = wr;   d = wrb;   j = i - c3; }
    const float4 a = reinterpret_cast<const float4*>(s)[2 * j];
    const float4 b = reinterpret_cast<const float4*>(s)[2 * j + 1];
    if (isobj) {  // out0 = obj passthrough, fused with the convert read
      reinterpret_cast<float4*>(out0)[2 * j] = a;
      reinterpret_cast<float4*>(out0)[2 * j + 1] = b;
    }
    u16x8 v;
    v[0] = f2bf(a.x); v[1] = f2bf(a.y); v[2] = f2bf(a.z); v[3] = f2bf(a.w);
    v[4] = f2bf(b.x); v[5] = f2bf(b.y); v[6] = f2bf(b.z); v[7] = f2bf(b.w);
    reinterpret_cast<u16x8*>(d)[j] = v;
  }
}

// ---------------------------------------------------------------------------
// 256x256 bf16 GEMM body, BK=32, 4-slot LDS ring, counted-vmcnt depth 3,
// ONE-PHASE-AHEAD register pipeline (m201 mechanism):
//   H0(t): issueA(t+3) | ds_read Af4-7(t) | MFMA mi0-3 (regs from H1(t-1))
//          | WAITV(6) [tile t+1 resident] | lgkmcnt(4) | barrier
//   H1(t): issueB(t+3) | ds_read B(t+1)+Af0-3(t+1)     | MFMA mi4-7
//          | lgkmcnt(8) | barrier
// MFMAs never wait on same-phase reads; counted lgkm at each boundary
// retires all reads >=1 phase old before any wave's overwriting gload (WAR,
// DS completes in-order); vmcnt drains only in the 3-tile tail.
// C[m,d] = relu(sum_k A[m,k]*W[d,k] + bias[d]) + resid[m,d]  (*mask[m] rela)
// A row = concat of 1024-wide segments (32 BK-tiles each):
//   attr: [objb m, attrb m]                      (K=2048, T=64)
//   rela: [objb[subj], relab m, objb[obji]]      (K=3072, T=96)
// LDS slot = A[256][32] + B[256][32] bf16 = 32 KB; 4 slots = 128 KB.
// Staging/read geometry bit-identical to rounds 4-6 (0 bank conflicts).
// ---------------------------------------------------------------------------
template <bool IS_RELA, int K_TOT, int LOG_RPB, int NPANEL>
__device__ __forceinline__ void gemm_body(
    int bid, unsigned short* smem,
    const unsigned short* __restrict__ objb,
    const unsigned short* __restrict__ seg1b,
    const unsigned short* __restrict__ Wb,
    const int* __restrict__ edges, const float* __restrict__ masks,
    const float* __restrict__ resid, const float* __restrict__ bias,
    float* __restrict__ out) {
  constexpr int T = K_TOT / 32;

  // XCD mapping: XCD x owns col panel (x>>1); (x&1) splits row panels.
  const int x = bid & 7;
  const int col0 = (x >> 1) * 256;
  const int panel = (x & 1) * (NPANEL / 2) + (bid >> 3);
  const int row0 = panel * 256;

  const int tid = threadIdx.x;
  const int w = tid >> 6;   // wave 0..7
  const int l = tid & 63;

  // staging: load r in {0,1} covers LDS rows (w*32 + r*16 + l>>2), granule
  // l&3 (16B); source granule pre-swizzle g = (l&3) ^ ((l>>3)&3) (rule #21).
  const int sw = (((l & 3) ^ ((l >> 3) & 3)) << 4);  // bytes
  uint32_t oA0[2], oA1[2], oA2[2], oB[2];
#pragma unroll
  for (int r = 0; r < 2; ++r) {
    const int rl = w * 32 + r * 16 + (l >> 2);
    const int m = row0 + rl;
    if constexpr (IS_RELA) {
      const int b = m >> LOG_RPB;
      const int ri = m & ((1 << LOG_RPB) - 1);
      const int2 e =
          *reinterpret_cast<const int2*>(&edges[((size_t)b * kR + ri) * 2]);
      oA0[r] = (uint32_t)((b * kN + e.x) * kD) * 2u;
      oA1[r] = (uint32_t)((size_t)m * kD * 2);
      oA2[r] = (uint32_t)((b * kN + e.y) * kD) * 2u;
    } else {
      oA0[r] = (uint32_t)((size_t)m * kD * 2);
      oA1[r] = oA0[r];
      oA2[r] = 0;
    }
    oB[r] = (uint32_t)((size_t)(col0 + rl) * K_TOT * 2);
  }

  const int wr = w >> 2;
  const int wc = w & 3;
  const int lrow = l & 15;
  const int lgrp = l >> 4;
  const int pgr = ((lgrp ^ ((lrow >> 1) & 3)) << 3);  // shorts

  f32x4 acc[8][4] = {};
  bf16x8 AfX[4], AfY[4], Bf0[4], Bf1[4];

  auto issueA = [&](int tn, int slot) {
    unsigned short* ra = smem + slot * 16384;
    const int seg = tn >> 5;                       // wave-uniform
    const uint32_t ko = (uint32_t)(tn & 31) << 6;  // bytes in segment row
#pragma unroll
    for (int r = 0; r < 2; ++r) {
      const char* srcA;
      if constexpr (IS_RELA) {
        srcA = (seg == 1) ? (const char*)seg1b + oA1[r]
                          : (const char*)objb + (seg == 0 ? oA0[r] : oA2[r]);
      } else {
        srcA = (seg == 0) ? (const char*)objb + oA0[r]
                          : (const char*)seg1b + oA1[r];
      }
      gload_lds16(srcA + ko + sw, ra + (w * 2 + r) * 512);
    }
  };
  auto issueB = [&](int tn, int slot) {
    unsigned short* rb = smem + slot * 16384 + 8192;
    const uint32_t kb2 = (uint32_t)tn << 6;        // bytes in W row
#pragma unroll
    for (int r = 0; r < 2; ++r)
      gload_lds16((const char*)Wb + oB[r] + kb2 + sw, rb + (w * 2 + r) * 512);
  };

#define RD_B4(SET, BASE)                                                   \
  _Pragma("unroll")                                                        \
  for (int ni = 0; ni < 4; ++ni)                                           \
    SET[ni] = *reinterpret_cast<const bf16x8*>(                            \
        &(BASE)[8192 + (wc * 64 + ni * 16 + lrow) * 32 + pgr]);

#define RD_A4(SET, BASE, MOFF)                                             \
  _Pragma("unroll")                                                        \
  for (int mi = 0; mi < 4; ++mi)                                           \
    SET[mi] = *reinterpret_cast<const bf16x8*>(                            \
        &(BASE)[(wr * 128 + ((MOFF) + mi) * 16 + lrow) * 32 + pgr]);

#define MFMA16(MOFF, ASET, BSET)                                           \
  __builtin_amdgcn_s_setprio(1);                                           \
  _Pragma("unroll")                                                        \
  for (int mi = 0; mi < 4; ++mi)                                           \
    _Pragma("unroll")                                                      \
    for (int ni = 0; ni < 4; ++ni)                                         \
      acc[(MOFF) + mi][ni] = __builtin_amdgcn_mfma_f32_16x16x32_bf16(      \
          ASET[mi], BSET[ni], acc[(MOFF) + mi][ni], 0, 0, 0);              \
  __builtin_amdgcn_s_setprio(0);

#define TILE(t, SLOT, BCUR, BNXT, DOI, WVTOK, LASTRD)                      \
  {                                                                        \
    const unsigned short* da_ = smem + (SLOT) * 16384;                     \
    const unsigned short* dn_ = smem + ((((SLOT) + 1) & 3) * 16384);       \
    if (DOI) issueA((t) + 3, ((SLOT) + 3) & 3);                            \
    RD_A4(AfY, da_, 4);                                                    \
    MFMA16(0, AfX, BCUR);                                                  \
    WAITV(WVTOK);                                                          \
    LGKM(4);                                                               \
    __builtin_amdgcn_s_barrier();                                          \
    FENCE;                                                                 \
    if (DOI) issueB((t) + 3, ((SLOT) + 3) & 3);                            \
    if (LASTRD) { RD_B4(BNXT, dn_); RD_A4(AfX, dn_, 0); }                  \
    MFMA16(4, AfY, BCUR);                                                  \
    LGKM(8);                                                               \
    __builtin_amdgcn_s_barrier();                                          \
    FENCE;                                                                 \
  }

  // prologue: 3 tiles in flight; tile 0 resident; tile-0 fragments in regs
  issueA(0, 0); issueB(0, 0);
  issueA(1, 1); issueB(1, 1);
  issueA(2, 2); issueB(2, 2);
  WAITV(8);  // tile 0 landed (12 outstanding -> 8)
  __builtin_amdgcn_s_barrier();
  FENCE;
  RD_B4(Bf0, smem);
  RD_A4(AfX, smem, 0);

  // main loop: tiles 0 .. T-5 (T % 4 == 0)
#pragma unroll 1
  for (int it = 0; it < (T - 4) / 4; ++it) {
    const int t = it * 4;
    TILE(t + 0, 0, Bf0, Bf1, true, 6, true);
    TILE(t + 1, 1, Bf1, Bf0, true, 6, true);
    TILE(t + 2, 2, Bf0, Bf1, true, 6, true);
    TILE(t + 3, 3, Bf1, Bf0, true, 6, true);
  }
  // tail: tiles T-4 .. T-1 (last issue targets tile T-1 in TILE(T-4))
  TILE(T - 4, 0, Bf0, Bf1, true, 6, true);
  TILE(T - 3, 1, Bf1, Bf0, false, 4, true);
  TILE(T - 2, 2, Bf0, Bf1, false, 0, true);
  TILE(T - 1, 3, Bf1, Bf0, false, 0, false);

#undef TILE
#undef MFMA16
#undef RD_A4
#undef RD_B4

  // epilogue: bias + relu + residual (+mask)
  float biasv[4];
#pragma unroll
  for (int ni = 0; ni < 4; ++ni)
    biasv[ni] = bias[col0 + wc * 64 + ni * 16 + lrow];

#pragma unroll
  for (int mi = 0; mi < 8; ++mi) {
#pragma unroll
    for (int jj = 0; jj < 4; ++jj) {
      const int m = row0 + wr * 128 + mi * 16 + lgrp * 4 + jj;
      const size_t ro = (size_t)m * kD;
      float mk = 1.0f;
      if constexpr (IS_RELA) mk = masks[m];
#pragma unroll
      for (int ni = 0; ni < 4; ++ni) {
        const int col = col0 + wc * 64 + ni * 16 + lrow;
        float v = acc[mi][ni][jj] + biasv[ni];
        v = fmaxf(v, 0.0f) + resid[ro + col];
        if constexpr (IS_RELA) v *= mk;
        out[ro + col] = v;
      }
    }
  }
}

// ---------------------------------------------------------------------------
// Fused launch: blocks 0..1023 = rela GEMM, 1024..1151 = attr GEMM.
// ---------------------------------------------------------------------------
__global__ __launch_bounds__(512, 2) void gnn_fused(
    const unsigned short* __restrict__ objb,
    const unsigned short* __restrict__ attrb,
    const unsigned short* __restrict__ relab,
    const unsigned short* __restrict__ wab,
    const unsigned short* __restrict__ wrb,
    const int* __restrict__ edges, const float* __restrict__ masks,
    const float* __restrict__ attr, const float* __restrict__ rela,
    const float* __restrict__ b_attr, const float* __restrict__ b_rela,
    float* __restrict__ out1, float* __restrict__ out2) {
  extern __shared__ unsigned short smem[];
  const int bid = blockIdx.x;
  if (bid < 1024) {
    gemm_body<true, 3072, 11, 256>(bid, smem, objb, relab, wrb, edges, masks,
                                   rela, b_rela, out2);
  } else {
    gemm_body<false, 2048, 8, 32>(bid - 1024, smem, objb, attrb, wab, nullptr,
                                  nullptr, attr, b_attr, out1);
  }
}

extern "C" void kernel_launch(void* const* d_in, const int* in_sizes, int n_in,
                              void* d_out, int out_size, void* d_ws,
                              size_t ws_size, hipStream_t stream) {
  (void)in_sizes; (void)n_in; (void)out_size; (void)ws_size;
  const float* obj = (const float*)d_in[0];
  const float* attr = (const float*)d_in[1];
  const float* rela = (const float*)d_in[2];
  const int* edges = (const int*)d_in[3];
  const float* masks = (const float*)d_in[4];
  const float* W_attr = (const float*)d_in[5];
  const float* b_attr = (const float*)d_in[6];
  const float* W_rela = (const float*)d_in[7];
  const float* b_rela = (const float*)d_in[8];

  float* out0 = (float*)d_out;
  float* out1 = out0 + (size_t)kB * kN * kD;
  float* out2 = out1 + (size_t)kB * kN * kD;

  constexpr size_t nObj = (size_t)kB * kN * kD;
  constexpr size_t nRela = (size_t)kB * kR * kD;
  constexpr size_t nWa = (size_t)kD * 2 * kD;

  unsigned short* objb = (unsigned short*)d_ws;
  unsigned short* attrb = objb + nObj;
  unsigned short* relab = attrb + nObj;
  unsigned short* wab = relab + nRela;
  unsigned short* wrb = wab + nWa;

  cvt_all<<<2048, 256, 0, stream>>>(obj, attr, rela, W_attr, W_rela, objb,
                                    attrb, relab, wab, wrb, out0);

  constexpr int kSmem = 131072;
  hipFuncSetAttribute((const void*)gnn_fused,
                      hipFuncAttributeMaxDynamicSharedMemorySize, kSmem);
  gnn_fused<<<1152, 512, kSmem, stream>>>(objb, attrb, relab, wab, wrb, edges,
                                          masks, attr, rela, b_attr, b_rela,
                                          out1, out2);
}

// Round 8
// 567.783 us; speedup vs baseline: 3.0214x; 1.0301x over previous
//
#include <hip/hip_runtime.h>
#include <hip/hip_bf16.h>

constexpr int kB = 32;
constexpr int kN = 256;
constexpr int kR = 2048;
constexpr int kD = 1024;

typedef short bf16x8 __attribute__((ext_vector_type(8)));
typedef float f32x4 __attribute__((ext_vector_type(4)));
typedef unsigned short u16x8 __attribute__((ext_vector_type(8)));

__device__ __forceinline__ unsigned short f2bf(float f) {
  union { __hip_bfloat16 h; unsigned short u; } cv;
  cv.h = __float2bfloat16(f);
  return cv.u;
}

__device__ __forceinline__ void gload_lds16(const void* g, void* l) {
  __builtin_amdgcn_global_load_lds(
      (const __attribute__((address_space(1))) unsigned int*)g,
      (__attribute__((address_space(3))) unsigned int*)l, 16, 0, 0);
}

#define FENCE asm volatile("" ::: "memory")
#define WAITV(n) asm volatile("s_waitcnt vmcnt(" #n ")" ::: "memory")

// ---------------------------------------------------------------------------
// Fused f32->bf16 pre-pass for all 5 GEMM operands + out0 passthrough copy.
// ---------------------------------------------------------------------------
__global__ void cvt_all(const float* __restrict__ obj,
                        const float* __restrict__ attr,
                        const float* __restrict__ rela,
                        const float* __restrict__ wa,
                        const float* __restrict__ wr,
                        unsigned short* __restrict__ objb,
                        unsigned short* __restrict__ attrb,
                        unsigned short* __restrict__ relab,
                        unsigned short* __restrict__ wab,
                        unsigned short* __restrict__ wrb,
                        float* __restrict__ out0) {
  constexpr long n0 = (long)kB * kN * kD / 8;          // obj
  constexpr long c0 = n0;
  constexpr long c1 = c0 + n0;                          // attr
  constexpr long c2 = c1 + (long)kB * kR * kD / 8;      // rela
  constexpr long c3 = c2 + (long)kD * 2 * kD / 8;       // W_attr
  constexpr long c4 = c3 + (long)kD * 3 * kD / 8;       // W_rela
  const long stride = (long)gridDim.x * blockDim.x;
  for (long i = (long)blockIdx.x * blockDim.x + threadIdx.x; i < c4;
       i += stride) {
    const float* s;
    unsigned short* d;
    long j;
    bool isobj = false;
    if (i < c0)      { s = obj;  d = objb;  j = i; isobj = true; }
    else if (i < c1) { s = attr; d = attrb; j = i - c0; }
    else if (i < c2) { s = rela; d = relab; j = i - c1; }
    else if (i < c3) { s = wa;   d = wab;   j = i - c2; }
    else             { s = wr;   d = wrb;   j = i - c3; }
    const float4 a = reinterpret_cast<const float4*>(s)[2 * j];
    const float4 b = reinterpret_cast<const float4*>(s)[2 * j + 1];
    if (isobj) {  // out0 = obj passthrough, fused with the convert read
      reinterpret_cast<float4*>(out0)[2 * j] = a;
      reinterpret_cast<float4*>(out0)[2 * j + 1] = b;
    }
    u16x8 v;
    v[0] = f2bf(a.x); v[1] = f2bf(a.y); v[2] = f2bf(a.z); v[3] = f2bf(a.w);
    v[4] = f2bf(b.x); v[5] = f2bf(b.y); v[6] = f2bf(b.z); v[7] = f2bf(b.w);
    reinterpret_cast<u16x8*>(d)[j] = v;
  }
}

// ---------------------------------------------------------------------------
// 256x256 bf16 GEMM body, BK=64 super-tiles = 2 proven BK=32 half-tiles,
// 2-slot LDS double buffer (2 x 64 KB), counted-vmcnt, one-phase-ahead reads.
// Per super-tile t (slot S=t&1), 4 sub-phases; issue order Ah0,Bh0,Ah1,Bh1
// of tile t+1 spread one-per-sub-phase:
//   sp0: issue Ah0(t+1) | pre-read A4-7@k0(t)        | MFMA k0 mi0-3
//   sp1: issue Bh0(t+1) | WAITV(4)+bar [Ah1,Bh1(t) resident]
//        | pre-read A0-3@k1 + B@k1 (t)               | MFMA k0 mi4-7
//   sp2: issue Ah1(t+1) | pre-read A4-7@k1(t)        | MFMA k1 mi0-3
//   sp3: issue Bh1(t+1) | WAITV(4)+bar [Ah0,Bh0(t+1) resident]
//        | pre-read A0-3@k0 + B@k0 (t+1, slot S^1)   | MFMA k1 mi4-7
// 2 barriers + 2 counted waits per 64 K-units (half the R7 rate); vmcnt
// never drains mid-loop; every staged round has >=2 sub-phases of slack.
// WAR: slot S^1 (written from sp0) holds tile t-1 whose last reads retired
// before t-1's final barrier (compiler-inserted lgkm before their MFMA).
// Staging/read/swizzle geometry per half-tile is bit-identical to rounds
// 4-7 (measured 0 bank conflicts).
// C[m,d] = relu(sum_k A[m,k]*W[d,k] + bias[d]) + resid[m,d]  (*mask[m] rela)
// A row = concat of 1024-wide segments:
//   attr: [objb m, attrb m]               (K=2048, T'=32)
//   rela: [objb[subj], relab m, objb[obji]] (K=3072, T'=48)
// ---------------------------------------------------------------------------
template <bool IS_RELA, int K_TOT, int LOG_RPB, int NPANEL>
__device__ __forceinline__ void gemm_body(
    int bid, unsigned short* smem,
    const unsigned short* __restrict__ objb,
    const unsigned short* __restrict__ seg1b,
    const unsigned short* __restrict__ Wb,
    const int* __restrict__ edges, const float* __restrict__ masks,
    const float* __restrict__ resid, const float* __restrict__ bias,
    float* __restrict__ out) {
  constexpr int T = K_TOT / 64;  // super-tiles

  // XCD mapping: XCD x owns col panel (x>>1); (x&1) splits row panels.
  const int x = bid & 7;
  const int col0 = (x >> 1) * 256;
  const int panel = (x & 1) * (NPANEL / 2) + (bid >> 3);
  const int row0 = panel * 256;

  const int tid = threadIdx.x;
  const int w = tid >> 6;   // wave 0..7
  const int l = tid & 63;

  // staging: round r in {0,1} of a half covers LDS rows (w*32 + r*16 + l>>2),
  // granule l&3 (16B); source pre-swizzle g = (l&3) ^ ((l>>3)&3) (rule #21).
  const int sw = (((l & 3) ^ ((l >> 3) & 3)) << 4);  // bytes
  const char* pA0[2];
  const char* pA1[2];
  const char* pA2[2];
  const char* pB[2];
#pragma unroll
  for (int r = 0; r < 2; ++r) {
    const int rl = w * 32 + r * 16 + (l >> 2);
    const int m = row0 + rl;
    if constexpr (IS_RELA) {
      const int b = m >> LOG_RPB;
      const int ri = m & ((1 << LOG_RPB) - 1);
      const int2 e =
          *reinterpret_cast<const int2*>(&edges[((size_t)b * kR + ri) * 2]);
      pA0[r] = (const char*)(objb + (size_t)(b * kN + e.x) * kD);
      pA1[r] = (const char*)(seg1b + (size_t)m * kD);
      pA2[r] = (const char*)(objb + (size_t)(b * kN + e.y) * kD);
    } else {
      pA0[r] = (const char*)(objb + (size_t)m * kD);
      pA1[r] = (const char*)(seg1b + (size_t)m * kD);
      pA2[r] = pA0[r];
    }
    pB[r] = (const char*)(Wb + (size_t)(col0 + rl) * K_TOT);
  }

  const int wr = w >> 2;
  const int wc = w & 3;
  const int lrow = l & 15;
  const int lgrp = l >> 4;
  const int pgr = ((lgrp ^ ((lrow >> 1) & 3)) << 3);  // shorts

  f32x4 acc[8][4] = {};
  bf16x8 AfX[4], AfY[4], Bf0[4], Bf1[4];

  // slot layout (shorts): S*32768 + { Ah0:0, Ah1:8192, Bh0:16384, Bh1:24576 }
  auto issueA = [&](int tn, int h, int slot) {
    unsigned short* ra = smem + slot * 32768 + h * 8192;
    const int kb = tn * 64 + h * 32;           // wave-uniform bf16 k-base
    const int seg = kb >> 10;
    const uint32_t ko = (uint32_t)(kb & 1023) * 2;
#pragma unroll
    for (int r = 0; r < 2; ++r) {
      const char* srcA;
      if constexpr (IS_RELA) {
        srcA = (seg == 1) ? pA1[r] : ((seg == 0) ? pA0[r] : pA2[r]);
      } else {
        srcA = (seg == 0) ? pA0[r] : pA1[r];
      }
      gload_lds16(srcA + ko + sw, ra + (w * 2 + r) * 512);
    }
  };
  auto issueB = [&](int tn, int h, int slot) {
    unsigned short* rb = smem + slot * 32768 + 16384 + h * 8192;
    const uint32_t kb2 = (uint32_t)(tn * 64 + h * 32) * 2;
#pragma unroll
    for (int r = 0; r < 2; ++r)
      gload_lds16(pB[r] + kb2 + sw, rb + (w * 2 + r) * 512);
  };

#define RD_A4(SET, SLOT, KK, MOFF)                                         \
  _Pragma("unroll")                                                        \
  for (int mi = 0; mi < 4; ++mi)                                           \
    SET[mi] = *reinterpret_cast<const bf16x8*>(                            \
        &smem[(SLOT) * 32768 + (KK) * 8192 +                               \
              (wr * 128 + ((MOFF) + mi) * 16 + lrow) * 32 + pgr]);

#define RD_B4(SET, SLOT, KK)                                               \
  _Pragma("unroll")                                                        \
  for (int ni = 0; ni < 4; ++ni)                                           \
    SET[ni] = *reinterpret_cast<const bf16x8*>(                            \
        &smem[(SLOT) * 32768 + 16384 + (KK) * 8192 +                       \
              (wc * 64 + ni * 16 + lrow) * 32 + pgr]);

#define MFMA16(MOFF, ASET, BSET)                                           \
  __builtin_amdgcn_s_setprio(1);                                           \
  _Pragma("unroll")                                                        \
  for (int mi = 0; mi < 4; ++mi)                                           \
    _Pragma("unroll")                                                      \
    for (int ni = 0; ni < 4; ++ni)                                         \
      acc[(MOFF) + mi][ni] = __builtin_amdgcn_mfma_f32_16x16x32_bf16(      \
          ASET[mi], BSET[ni], acc[(MOFF) + mi][ni], 0, 0, 0);              \
  __builtin_amdgcn_s_setprio(0);

// Super-tile t in slot S (compile-time 0/1); issues tile t+1 into S^1.
#define STILE(t, S)                                                        \
  {                                                                        \
    /* sp0 */                                                              \
    issueA((t) + 1, 0, (S) ^ 1);                                           \
    RD_A4(AfY, S, 0, 4);                                                   \
    MFMA16(0, AfX, Bf0);                                                   \
    /* sp1 */                                                              \
    issueB((t) + 1, 0, (S) ^ 1);                                           \
    WAITV(4);                                                              \
    __builtin_amdgcn_s_barrier();                                          \
    FENCE;                                                                 \
    RD_A4(AfX, S, 1, 0);                                                   \
    RD_B4(Bf1, S, 1);                                                      \
    MFMA16(4, AfY, Bf0);                                                   \
    /* sp2 */                                                              \
    issueA((t) + 1, 1, (S) ^ 1);                                           \
    RD_A4(AfY, S, 1, 4);                                                   \
    MFMA16(0, AfX, Bf1);                                                   \
    /* sp3 */                                                              \
    issueB((t) + 1, 1, (S) ^ 1);                                           \
    WAITV(4);                                                              \
    __builtin_amdgcn_s_barrier();                                          \
    FENCE;                                                                 \
    RD_A4(AfX, (S) ^ 1, 0, 0);                                             \
    RD_B4(Bf0, (S) ^ 1, 0);                                                \
    MFMA16(4, AfY, Bf1);                                                   \
  }

  // prologue: tile 0's four halves in steady-state order; half-0 resident.
  issueA(0, 0, 0); issueB(0, 0, 0);
  issueA(0, 1, 0); issueB(0, 1, 0);
  WAITV(4);  // Ah0,Bh0(0) landed; Ah1,Bh1(0) in flight
  __builtin_amdgcn_s_barrier();
  FENCE;
  RD_A4(AfX, 0, 0, 0);
  RD_B4(Bf0, 0, 0);

  // main loop: super-tiles 0 .. T-2 (T even: 48 rela / 32 attr)
#pragma unroll 1
  for (int it = 0; it < (T - 2) / 2; ++it) {
    STILE(2 * it, 0);
    STILE(2 * it + 1, 1);
  }
  STILE(T - 2, 0);  // issues tile T-1 into slot 1

  // tail: super-tile T-1 in slot 1, no issues.
  {
    RD_A4(AfY, 1, 0, 4);            // sp0
    MFMA16(0, AfX, Bf0);
    WAITV(0);                       // sp1: drain Ah1,Bh1(T-1)
    __builtin_amdgcn_s_barrier();
    FENCE;
    RD_A4(AfX, 1, 1, 0);
    RD_B4(Bf1, 1, 1);
    MFMA16(4, AfY, Bf0);
    RD_A4(AfY, 1, 1, 4);            // sp2
    MFMA16(0, AfX, Bf1);
    MFMA16(4, AfY, Bf1);            // sp3
  }

#undef STILE
#undef MFMA16
#undef RD_B4
#undef RD_A4

  // epilogue: bias + relu + residual (+mask)
  float biasv[4];
#pragma unroll
  for (int ni = 0; ni < 4; ++ni)
    biasv[ni] = bias[col0 + wc * 64 + ni * 16 + lrow];

#pragma unroll
  for (int mi = 0; mi < 8; ++mi) {
#pragma unroll
    for (int jj = 0; jj < 4; ++jj) {
      const int m = row0 + wr * 128 + mi * 16 + lgrp * 4 + jj;
      const size_t ro = (size_t)m * kD;
      float mk = 1.0f;
      if constexpr (IS_RELA) mk = masks[m];
#pragma unroll
      for (int ni = 0; ni < 4; ++ni) {
        const int col = col0 + wc * 64 + ni * 16 + lrow;
        float v = acc[mi][ni][jj] + biasv[ni];
        v = fmaxf(v, 0.0f) + resid[ro + col];
        if constexpr (IS_RELA) v *= mk;
        out[ro + col] = v;
      }
    }
  }
}

// ---------------------------------------------------------------------------
// Fused launch: blocks 0..1023 = rela GEMM, 1024..1151 = attr GEMM.
// ---------------------------------------------------------------------------
__global__ __launch_bounds__(512, 2) void gnn_fused(
    const unsigned short* __restrict__ objb,
    const unsigned short* __restrict__ attrb,
    const unsigned short* __restrict__ relab,
    const unsigned short* __restrict__ wab,
    const unsigned short* __restrict__ wrb,
    const int* __restrict__ edges, const float* __restrict__ masks,
    const float* __restrict__ attr, const float* __restrict__ rela,
    const float* __restrict__ b_attr, const float* __restrict__ b_rela,
    float* __restrict__ out1, float* __restrict__ out2) {
  extern __shared__ unsigned short smem[];
  const int bid = blockIdx.x;
  if (bid < 1024) {
    gemm_body<true, 3072, 11, 256>(bid, smem, objb, relab, wrb, edges, masks,
                                   rela, b_rela, out2);
  } else {
    gemm_body<false, 2048, 8, 32>(bid - 1024, smem, objb, attrb, wab, nullptr,
                                  nullptr, attr, b_attr, out1);
  }
}

extern "C" void kernel_launch(void* const* d_in, const int* in_sizes, int n_in,
                              void* d_out, int out_size, void* d_ws,
                              size_t ws_size, hipStream_t stream) {
  (void)in_sizes; (void)n_in; (void)out_size; (void)ws_size;
  const float* obj = (const float*)d_in[0];
  const float* attr = (const float*)d_in[1];
  const float* rela = (const float*)d_in[2];
  const int* edges = (const int*)d_in[3];
  const float* masks = (const float*)d_in[4];
  const float* W_attr = (const float*)d_in[5];
  const float* b_attr = (const float*)d_in[6];
  const float* W_rela = (const float*)d_in[7];
  const float* b_rela = (const float*)d_in[8];

  float* out0 = (float*)d_out;
  float* out1 = out0 + (size_t)kB * kN * kD;
  float* out2 = out1 + (size_t)kB * kN * kD;

  constexpr size_t nObj = (size_t)kB * kN * kD;
  constexpr size_t nRela = (size_t)kB * kR * kD;
  constexpr size_t nWa = (size_t)kD * 2 * kD;

  unsigned short* objb = (unsigned short*)d_ws;
  unsigned short* attrb = objb + nObj;
  unsigned short* relab = attrb + nObj;
  unsigned short* wab = relab + nRela;
  unsigned short* wrb = wab + nWa;

  cvt_all<<<2048, 256, 0, stream>>>(obj, attr, rela, W_attr, W_rela, objb,
                                    attrb, relab, wab, wrb, out0);

  constexpr int kSmem = 131072;
  hipFuncSetAttribute((const void*)gnn_fused,
                      hipFuncAttributeMaxDynamicSharedMemorySize, kSmem);
  gnn_fused<<<1152, 512, kSmem, stream>>>(objb, attrb, relab, wab, wrb, edges,
                                          masks, attr, rela, b_attr, b_rela,
                                          out1, out2);
}